// Round 1
// baseline (3055.496 us; speedup 1.0000x reference)
//
#include <hip/hip_runtime.h>
#include <math.h>

// RAMEN layer, f32 correctness-first implementation.
// T=2048, X_D=2048, M_D=256, M_N=64, CHUNK=64, FF_D=2816.

#define T_TOK 2048
#define X_DIM 2048
#define M_DIM 256
#define M_NUM 64
#define FF_DIM 2816

__device__ __forceinline__ float sigmoidf_(float x){ return 1.0f/(1.0f+expf(-x)); }

// ---------------- scale norm: o[r,:] = x[r,:] * g / (||x[r,:]|| + 1e-8) ---------
__global__ __launch_bounds__(256) void k_scalenorm(const float* __restrict__ x,
    const float* __restrict__ g, float* __restrict__ o){
  int row = blockIdx.x, tid = threadIdx.x;
  const float* xr = x + (size_t)row*X_DIM;
  float ss = 0.f;
  for (int j = tid; j < X_DIM; j += 256){ float v = xr[j]; ss += v*v; }
  __shared__ float red[256];
  red[tid] = ss; __syncthreads();
  for (int s = 128; s > 0; s >>= 1){ if (tid < s) red[tid] += red[tid+s]; __syncthreads(); }
  float scale = g[0] / (sqrtf(red[0]) + 1e-8f);
  float* orow = o + (size_t)row*X_DIM;
  for (int j = tid; j < X_DIM; j += 256) orow[j] = xr[j]*scale;
}

// ---------------- generic tiled f32 GEMM ----------------------------------------
// C[M,N] = A[M,K] @ opB (+ add).  transb=1: B is [N,K] (C=A@B^T).  transb=0: B is [K,N].
// epi: 0=none, 1=sigmoid(v), 2=v*sigmoid(gate[idx])  (gate may alias C; same-index only)
// Requires M%64==0, N%64==0, K%16==0, K%4==0, N%4==0.
__global__ __launch_bounds__(256) void k_gemm(const float* __restrict__ A,
    const float* __restrict__ B, float* __restrict__ C,
    int M, int N, int K, int transb, int epi,
    const float* __restrict__ add, const float* __restrict__ gate){
  __shared__ float As[16][64];
  __shared__ float Bs[16][64];
  int tid = threadIdx.x;
  int bi = blockIdx.y, bj = blockIdx.x;
  int tx = tid & 15, ty = tid >> 4;
  int arow = tid >> 2, akq = (tid & 3) << 2;
  int bk = tid >> 4, bnq = (tid & 15) << 2;
  float acc[4][4] = {{0.f}};
  for (int kt = 0; kt < K; kt += 16){
    float4 av = *(const float4*)(A + (size_t)(bi*64 + arow)*K + kt + akq);
    As[akq+0][arow]=av.x; As[akq+1][arow]=av.y; As[akq+2][arow]=av.z; As[akq+3][arow]=av.w;
    if (transb){
      float4 bv = *(const float4*)(B + (size_t)(bj*64 + arow)*K + kt + akq);
      Bs[akq+0][arow]=bv.x; Bs[akq+1][arow]=bv.y; Bs[akq+2][arow]=bv.z; Bs[akq+3][arow]=bv.w;
    } else {
      float4 bv = *(const float4*)(B + (size_t)(kt + bk)*N + bj*64 + bnq);
      Bs[bk][bnq+0]=bv.x; Bs[bk][bnq+1]=bv.y; Bs[bk][bnq+2]=bv.z; Bs[bk][bnq+3]=bv.w;
    }
    __syncthreads();
#pragma unroll
    for (int k = 0; k < 16; ++k){
      float a[4], b[4];
#pragma unroll
      for (int u = 0; u < 4; ++u) a[u] = As[k][ty*4+u];
#pragma unroll
      for (int u = 0; u < 4; ++u) b[u] = Bs[k][tx*4+u];
#pragma unroll
      for (int i = 0; i < 4; ++i)
#pragma unroll
        for (int j = 0; j < 4; ++j) acc[i][j] = fmaf(a[i], b[j], acc[i][j]);
    }
    __syncthreads();
  }
#pragma unroll
  for (int i = 0; i < 4; ++i){
#pragma unroll
    for (int j = 0; j < 4; ++j){
      size_t idx = (size_t)(bi*64 + ty*4 + i)*N + bj*64 + tx*4 + j;
      float v = acc[i][j];
      if (add)  v += add[idx];
      if (epi == 1) v = sigmoidf_(v);
      else if (epi == 2) v *= sigmoidf_(gate[idx]);
      C[idx] = v;
    }
  }
}

// ---------------- RoPE: Q in-place (pos 64+i), KA (pos 64+i), KB (pos i) --------
__global__ void k_rope(float* __restrict__ Q, const float* __restrict__ K0,
                       float* __restrict__ KA, float* __restrict__ KB){
  int t = blockIdx.x, j = threadIdx.x;   // j in [0,128): pair index
  int i = t & 63;
  float inv = powf(10000.f, -(float)(2*j)/256.f);
  float aa = (float)(i + 64)*inv;
  float ab = (float)i*inv;
  float ca = cosf(aa), sa = sinf(aa);
  float cb = cosf(ab), sb = sinf(ab);
  size_t base = (size_t)t*256 + 2*j;
  float q0 = Q[base], q1 = Q[base+1];
  Q[base]   = q0*ca - q1*sa;
  Q[base+1] = q1*ca + q0*sa;
  float k0 = K0[base], k1 = K0[base+1];
  KA[base]   = k0*ca - k1*sa;
  KA[base+1] = k1*ca + k0*sa;
  KB[base]   = k0*cb - k1*sb;
  KB[base+1] = k1*cb + k0*sb;
}

// ---------------- attention scores + softmax -> P[c][64][128] -------------------
__global__ __launch_bounds__(256) void k_attn_scores(const float* __restrict__ Q,
    const float* __restrict__ KA, const float* __restrict__ KB, float* __restrict__ P){
  __shared__ float S[64][128];
  int c = blockIdx.x, tid = threadIdx.x;
  for (int idx = tid; idx < 64*128; idx += 256){
    int i = idx >> 7, m = idx & 127;
    float s;
    if (m > i + 64){
      s = -INFINITY;                       // masked
    } else if (m < 64 && c == 0){
      s = 0.f;                             // zero prev-chunk keys
    } else {
      const float* qr = Q + ((size_t)c*64 + i)*256;
      const float* kr = (m < 64) ? (KB + ((size_t)(c-1)*64 + m)*256)
                                 : (KA + ((size_t)c*64 + (m-64))*256);
      float acc = 0.f;
      for (int d = 0; d < 256; d += 4){
        float4 qv = *(const float4*)(qr + d);
        float4 kv = *(const float4*)(kr + d);
        acc += qv.x*kv.x + qv.y*kv.y + qv.z*kv.z + qv.w*kv.w;
      }
      s = acc * (1.f/16.f);
    }
    S[i][m] = s;
  }
  __syncthreads();
  if (tid < 64){
    int i = tid;
    float mx = -INFINITY;
    for (int m = 0; m < 128; ++m) mx = fmaxf(mx, S[i][m]);
    float sum = 0.f;
    for (int m = 0; m < 128; ++m){
      float v = S[i][m];
      float e = (v == -INFINITY) ? 0.f : expf(v - mx);
      S[i][m] = e; sum += e;
    }
    float r = 1.f/sum;
    float* pr = P + ((size_t)c*64 + i)*128;
    for (int m = 0; m < 128; ++m) pr[m] = S[i][m]*r;
  }
}

// ---------------- Y[c*64+i, :] = sum_m P[c,i,m] * V2[c,m,:] ---------------------
__global__ __launch_bounds__(256) void k_attn_pv(const float* __restrict__ P,
    const float* __restrict__ V, float* __restrict__ Y){
  __shared__ float Pl[64][128];
  __shared__ float Vt[128][64];
  int ct = blockIdx.x, c = blockIdx.y;
  int tid = threadIdx.x;
  for (int q = tid; q < 2048; q += 256)
    ((float4*)&Pl[0][0])[q] = ((const float4*)(P + (size_t)c*8192))[q];
  for (int q = tid; q < 2048; q += 256){
    int r = q >> 4, cq = (q & 15) << 2;
    float4 v;
    if (c == 0 && r < 64) v = make_float4(0.f,0.f,0.f,0.f);
    else {
      int gr = (c-1)*64 + r;
      v = *(const float4*)(V + (size_t)gr*X_DIM + ct*64 + cq);
    }
    *(float4*)&Vt[r][cq] = v;
  }
  __syncthreads();
  int tx = tid & 15, ty = tid >> 4;
  float acc[4][4] = {{0.f}};
  for (int m = 0; m < 128; ++m){
    float a[4], b[4];
#pragma unroll
    for (int u=0;u<4;++u) a[u] = Pl[ty*4+u][m];
#pragma unroll
    for (int u=0;u<4;++u) b[u] = Vt[m][tx*4+u];
#pragma unroll
    for (int i=0;i<4;++i)
#pragma unroll
      for (int j=0;j<4;++j) acc[i][j] = fmaf(a[i], b[j], acc[i][j]);
  }
#pragma unroll
  for (int i=0;i<4;++i)
#pragma unroll
    for (int j=0;j<4;++j)
      Y[(size_t)(c*64 + ty*4 + i)*X_DIM + ct*64 + tx*4 + j] = acc[i][j];
}

// ---------------- mem scan (3-phase blocked): state s[t] = w[t]*s[t-1] + b[t] ---
__global__ __launch_bounds__(256) void k_scan1(const float* __restrict__ FG,
    const float* __restrict__ VM, const float* __restrict__ beta_p,
    const float* __restrict__ decay_p, float* __restrict__ CP, float* __restrict__ CQ){
  int c = blockIdx.x, m = blockIdx.y, d = threadIdx.x;
  float beta  = sigmoidf_(beta_p[m*256 + d]);
  float gamma = (d < 192) ? 1.f : sigmoidf_(decay_p[m*64 + (d-192)]);
  float Pa = 1.f, Qa = 0.f;
  for (int s = 0; s < 64; ++s){
    int t = c*64 + s;
    float f = FG[(size_t)t*64 + m];
    float w = (1.f - f*beta)*gamma;
    Pa *= w;
    Qa = w*Qa + f*VM[(size_t)t*256 + d];
  }
  size_t idx = ((size_t)c*64 + m)*256 + d;
  CP[idx] = Pa; CQ[idx] = Qa;
}

__global__ __launch_bounds__(256) void k_scan2(const float* __restrict__ CP,
    const float* __restrict__ CQ, float* __restrict__ SIN){
  int m = blockIdx.x, d = threadIdx.x;
  float S = 0.f;
  for (int c = 0; c < 32; ++c){
    size_t idx = ((size_t)c*64 + m)*256 + d;
    SIN[idx] = S;
    S = CP[idx]*S + CQ[idx];
  }
}

__global__ __launch_bounds__(256) void k_scan3(const float* __restrict__ FG,
    const float* __restrict__ VM, const float* __restrict__ beta_p,
    const float* __restrict__ decay_p, const float* __restrict__ SIN,
    float* __restrict__ MEMS){
  int c = blockIdx.x, m = blockIdx.y, d = threadIdx.x;
  float beta  = sigmoidf_(beta_p[m*256 + d]);
  float gamma = (d < 192) ? 1.f : sigmoidf_(decay_p[m*64 + (d-192)]);
  float S = SIN[((size_t)c*64 + m)*256 + d];
  for (int s = 0; s < 64; ++s){
    int t = c*64 + s;
    float f = FG[(size_t)t*64 + m];
    float w = (1.f - f*beta)*gamma;
    S = w*S + f*VM[(size_t)t*256 + d];
    MEMS[((size_t)t*64 + m)*256 + d] = S;
  }
}

// ---------------- mem readout: scores (mems.qh + l.qm)/16, softmax, weighted sum
__global__ __launch_bounds__(256) void k_memread(const float* __restrict__ MEMS,
    const float* __restrict__ QH, const float* __restrict__ QM,
    const float* __restrict__ L, float* __restrict__ YM){
  int t = blockIdx.x, tid = threadIdx.x;
  int wave = tid >> 6, lane = tid & 63;
  __shared__ float anorm[64];
  const float* Mt = MEMS + (size_t)t*16384;
  float4 qh4 = *(const float4*)(QH + (size_t)t*256 + lane*4);
  float4 qm4 = *(const float4*)(QM + (size_t)t*256 + lane*4);
  for (int mi = 0; mi < 16; ++mi){
    int m = wave*16 + mi;
    float4 s4 = *(const float4*)(Mt + m*256 + lane*4);
    float4 l4 = *(const float4*)(L + (size_t)m*256 + lane*4);
    float p = s4.x*qh4.x + s4.y*qh4.y + s4.z*qh4.z + s4.w*qh4.w
            + l4.x*qm4.x + l4.y*qm4.y + l4.z*qm4.z + l4.w*qm4.w;
#pragma unroll
    for (int off = 32; off > 0; off >>= 1) p += __shfl_down(p, off);
    if (lane == 0) anorm[m] = p * (1.f/16.f);
  }
  __syncthreads();
  if (tid == 0){
    float mx = -INFINITY;
    for (int i = 0; i < 64; ++i) mx = fmaxf(mx, anorm[i]);
    float sum = 0.f;
    for (int i = 0; i < 64; ++i){ float e = expf(anorm[i]-mx); anorm[i] = e; sum += e; }
    float r = 1.f/sum;
    for (int i = 0; i < 64; ++i) anorm[i] *= r;
  }
  __syncthreads();
  float acc = 0.f;
  for (int m = 0; m < 64; ++m) acc += anorm[m]*Mt[m*256 + tid];
  YM[(size_t)t*256 + tid] = acc;
}

// ---------------- elementwise helpers -------------------------------------------
__global__ void k_add3(const float* __restrict__ a, const float* __restrict__ b,
                       const float* __restrict__ c, float* __restrict__ o, int n4){
  int i = blockIdx.x*256 + threadIdx.x;
  if (i < n4){
    float4 x = ((const float4*)a)[i], y = ((const float4*)b)[i], z = ((const float4*)c)[i];
    float4 r; r.x=x.x+y.x+z.x; r.y=x.y+y.y+z.y; r.z=x.z+y.z+z.z; r.w=x.w+y.w+z.w;
    ((float4*)o)[i] = r;
  }
}

__global__ void k_silumul(float* __restrict__ h1, const float* __restrict__ h2, int n4){
  int i = blockIdx.x*256 + threadIdx.x;
  if (i < n4){
    float4 a = ((float4*)h1)[i]; float4 b = ((const float4*)h2)[i];
    a.x = a.x*sigmoidf_(a.x)*b.x;
    a.y = a.y*sigmoidf_(a.y)*b.y;
    a.z = a.z*sigmoidf_(a.z)*b.z;
    a.w = a.w*sigmoidf_(a.w)*b.w;
    ((float4*)h1)[i] = a;
  }
}

// ---------------- launch ---------------------------------------------------------
extern "C" void kernel_launch(void* const* d_in, const int* in_sizes, int n_in,
                              void* d_out, int out_size, void* d_ws, size_t ws_size,
                              hipStream_t stream){
  const float* xs        = (const float*)d_in[0];
  const float* attn_q    = (const float*)d_in[1];
  const float* attn_k    = (const float*)d_in[2];
  const float* attn_v    = (const float*)d_in[3];
  const float* attn_o    = (const float*)d_in[4];
  const float* attn_r    = (const float*)d_in[5];
  const float* mem_f     = (const float*)d_in[6];
  const float* mem_q     = (const float*)d_in[7];
  const float* mem_k     = (const float*)d_in[8];
  const float* mem_v     = (const float*)d_in[9];
  const float* mem_o     = (const float*)d_in[10];
  const float* mem_r     = (const float*)d_in[11];
  const float* mem_beta  = (const float*)d_in[12];
  const float* mem_decay = (const float*)d_in[13];
  const float* mem_l     = (const float*)d_in[14];
  const float* ff1       = (const float*)d_in[15];
  const float* ff2       = (const float*)d_in[16];
  const float* ffo       = (const float*)d_in[17];
  const float* sn1       = (const float*)d_in[18];
  const float* sn2       = (const float*)d_in[19];
  float* out = (float*)d_out;
  float* W = (float*)d_ws;

  // workspace layout (float offsets); peak ~242 MB
  float* XN   = W + 0;          // 4194304
  float* V    = W + 4194304;    // 4194304 (freed after PV -> aliased by scan carries)
  float* Qb   = W + 8388608;    // 524288
  float* K0   = W + 8912896;    // 524288
  float* KA   = W + 9437184;    // 524288
  float* KB   = W + 9961472;    // 524288
  float* P    = W + 10485760;   // 262144
  float* Yb   = W + 10747904;   // 4194304 (freed after AO -> aliased by XN2)
  float* B1   = W + 14942208;   // 4194304 attn gate/out
  float* B2   = W + 19136512;   // 4194304 mem gate/out
  float* XS2  = W + 23330816;   // 4194304
  float* VM   = W + 27525120;   // 524288
  float* FG   = W + 28049408;   // 131072
  float* QM   = W + 28180480;   // 524288
  float* QH   = W + 28704768;   // 524288
  float* YM   = W + 29229056;   // 524288
  float* MEMS = W + 29753344;   // 33554432 (freed after readout -> aliased by H1/H2)
  float* CP   = V;              // 524288
  float* CQ   = V + 524288;     // 524288
  float* SIN  = V + 1048576;    // 524288
  float* H1   = MEMS;           // 5767168
  float* H2   = MEMS + 5767168; // 5767168
  float* XN2  = Yb;

  dim3 blk(256);

  // xn = scale_norm(xs, g1)
  k_scalenorm<<<dim3(2048), blk, 0, stream>>>(xs, sn1, XN);

  // ---- attention ----
  k_gemm<<<dim3(4, 32), blk, 0, stream>>>(XN, attn_q, Qb, 2048, 256, 2048, 1, 0, nullptr, nullptr);
  k_gemm<<<dim3(4, 32), blk, 0, stream>>>(Qb, attn_k, K0, 2048, 256, 256, 1, 0, nullptr, nullptr);
  k_rope<<<dim3(2048), dim3(128), 0, stream>>>(Qb, K0, KA, KB);
  k_gemm<<<dim3(32, 32), blk, 0, stream>>>(XN, attn_v, V, 2048, 2048, 2048, 1, 0, nullptr, nullptr);
  k_attn_scores<<<dim3(32), blk, 0, stream>>>(Qb, KA, KB, P);
  k_attn_pv<<<dim3(32, 32), blk, 0, stream>>>(P, V, Yb);
  // B1 = xn@Wr^T ; then B1 = (Y@Wo^T)*sigmoid(B1)
  k_gemm<<<dim3(32, 32), blk, 0, stream>>>(XN, attn_r, B1, 2048, 2048, 2048, 1, 0, nullptr, nullptr);
  k_gemm<<<dim3(32, 32), blk, 0, stream>>>(Yb, attn_o, B1, 2048, 2048, 2048, 1, 2, nullptr, B1);

  // ---- memory branch ----
  k_gemm<<<dim3(4, 32), blk, 0, stream>>>(XN, mem_v, VM, 2048, 256, 2048, 1, 0, nullptr, nullptr);
  k_gemm<<<dim3(1, 32), blk, 0, stream>>>(XN, mem_f, FG, 2048, 64, 2048, 1, 1, nullptr, nullptr);
  k_gemm<<<dim3(4, 32), blk, 0, stream>>>(XN, mem_q, QM, 2048, 256, 2048, 1, 0, nullptr, nullptr);
  k_gemm<<<dim3(4, 32), blk, 0, stream>>>(QM, mem_k, QH, 2048, 256, 256, 0, 0, nullptr, nullptr); // qh = qm @ Wk
  k_scan1<<<dim3(32, 64), blk, 0, stream>>>(FG, VM, mem_beta, mem_decay, CP, CQ);
  k_scan2<<<dim3(64), blk, 0, stream>>>(CP, CQ, SIN);
  k_scan3<<<dim3(32, 64), blk, 0, stream>>>(FG, VM, mem_beta, mem_decay, SIN, MEMS);
  k_memread<<<dim3(2048), blk, 0, stream>>>(MEMS, QH, QM, mem_l, YM);
  // B2 = xn@memr^T ; then B2 = (YM@memo^T)*sigmoid(B2)
  k_gemm<<<dim3(32, 32), blk, 0, stream>>>(XN, mem_r, B2, 2048, 2048, 2048, 1, 0, nullptr, nullptr);
  k_gemm<<<dim3(32, 32), blk, 0, stream>>>(YM, mem_o, B2, 2048, 2048, 256, 1, 2, nullptr, B2);

  // xs2 = attn_out + mem_out + xs
  k_add3<<<dim3(4096), blk, 0, stream>>>(B1, B2, xs, XS2, 1048576);

  // ---- FF ----
  k_scalenorm<<<dim3(2048), blk, 0, stream>>>(XS2, sn2, XN2);
  k_gemm<<<dim3(44, 32), blk, 0, stream>>>(XN2, ff1, H1, 2048, 2816, 2048, 1, 0, nullptr, nullptr);
  k_gemm<<<dim3(44, 32), blk, 0, stream>>>(XN2, ff2, H2, 2048, 2816, 2048, 1, 0, nullptr, nullptr);
  k_silumul<<<dim3(5632), blk, 0, stream>>>(H1, H2, 1441792);
  // out = H @ ffo^T + xs2
  k_gemm<<<dim3(32, 32), blk, 0, stream>>>(H1, ffo, out, 2048, 2048, 2816, 1, 0, XS2, nullptr);
}

// Round 2
// 874.374 us; speedup vs baseline: 3.4945x; 3.4945x over previous
//
#include <hip/hip_runtime.h>
#include <math.h>

// RAMEN layer. Round 2: bf16 MFMA for all big GEMMs (concat-fused), bf16 MEMS,
// restructured scan. T=2048, X_D=2048, M_D=256, M_N=64, CHUNK=64, FF_D=2816.

typedef short bhalf8 __attribute__((ext_vector_type(8)));
typedef float f32x4 __attribute__((ext_vector_type(4)));

#define CC_LD 7040   // concat GEMM output row stride
#define COL_V   0
#define COL_B1  2048
#define COL_B2  4096
#define COL_QB  6144
#define COL_VM  6400
#define COL_QM  6656
#define COL_FG  6912

__device__ __forceinline__ float sigmoidf_(float x){ return 1.0f/(1.0f+expf(-x)); }

__device__ __forceinline__ unsigned short f2b(float f){
  unsigned u = __float_as_uint(f);
  unsigned r = (u + 0x7fffu + ((u>>16)&1u)) >> 16;
  return (unsigned short)r;
}
__device__ __forceinline__ float b2f(unsigned short h){
  return __uint_as_float(((unsigned)h)<<16);
}

// ---------------- f32 -> bf16 convert (4 elems/thread) --------------------------
__global__ void k_f2b(const float* __restrict__ s, unsigned short* __restrict__ d, int n4){
  int i = blockIdx.x*256 + threadIdx.x;
  if (i < n4){
    float4 v = ((const float4*)s)[i];
    ushort4 o;
    o.x = f2b(v.x); o.y = f2b(v.y); o.z = f2b(v.z); o.w = f2b(v.w);
    ((ushort4*)d)[i] = o;
  }
}

// ---------------- scale norm -> bf16 --------------------------------------------
__global__ __launch_bounds__(256) void k_scalenorm_b(const float* __restrict__ x,
    const float* __restrict__ g, unsigned short* __restrict__ ob){
  int row = blockIdx.x, tid = threadIdx.x;
  const float* xr = x + (size_t)row*2048;
  float ss = 0.f;
  for (int j = tid; j < 2048; j += 256){ float v = xr[j]; ss += v*v; }
  __shared__ float red[256];
  red[tid] = ss; __syncthreads();
  for (int s = 128; s > 0; s >>= 1){ if (tid < s) red[tid] += red[tid+s]; __syncthreads(); }
  float scale = g[0] / (sqrtf(red[0]) + 1e-8f);
  unsigned short* orow = ob + (size_t)row*2048;
  for (int j4 = tid; j4 < 512; j4 += 256){
    float4 v = *(const float4*)(xr + j4*4);
    ushort4 o;
    o.x = f2b(v.x*scale); o.y = f2b(v.y*scale); o.z = f2b(v.z*scale); o.w = f2b(v.w*scale);
    ((ushort4*)orow)[j4] = o;
  }
}

// ---------------- bf16 MFMA GEMM: C[M,N] = A[M,K] @ B[N,K]^T --------------------
// 128x128 tile, BK=32, 4 waves (2x2), global_load_lds staging.
// epi: 0 none, 2: v *= sigmoid(gate[row*gate_ld+col]).  add: optional residual (ld=N).
__global__ __launch_bounds__(256) void k_gemm_bf(
    const unsigned short* __restrict__ A, const unsigned short* __restrict__ B,
    float* __restrict__ C, int N, int K, int epi,
    const float* __restrict__ add, const float* __restrict__ gate, int gate_ld){
  __shared__ unsigned short As[128*32];
  __shared__ unsigned short Bs[128*32];
  int tid = threadIdx.x;
  int w = tid >> 6, l = tid & 63;
  int bi = blockIdx.y, bj = blockIdx.x;
  int m0 = bi*128, n0 = bj*128;
  int wr = w >> 1, wc = w & 1;

  f32x4 acc[4][4];
#pragma unroll
  for (int i=0;i<4;++i)
#pragma unroll
    for (int j=0;j<4;++j){ f32x4 z = {0.f,0.f,0.f,0.f}; acc[i][j] = z; }

  int q0 = (w*2+0)*64 + l, q1 = (w*2+1)*64 + l;
  int ar0 = q0>>2, ac0 = (q0&3)*8;
  int ar1 = q1>>2, ac1 = (q1&3)*8;
  const unsigned short* a0 = A + (size_t)(m0+ar0)*K + ac0;
  const unsigned short* a1 = A + (size_t)(m0+ar1)*K + ac1;
  const unsigned short* b0 = B + (size_t)(n0+ar0)*K + ac0;
  const unsigned short* b1 = B + (size_t)(n0+ar1)*K + ac1;
  unsigned short* As0 = As + (w*2+0)*512;
  unsigned short* As1 = As + (w*2+1)*512;
  unsigned short* Bs0 = Bs + (w*2+0)*512;
  unsigned short* Bs1 = Bs + (w*2+1)*512;
  int lrow = l & 15, lk = (l>>4)*8;

  for (int kt = 0; kt < K; kt += 32){
    __builtin_amdgcn_global_load_lds((const __attribute__((address_space(1))) void*)(a0 + kt),
        (__attribute__((address_space(3))) void*)As0, 16, 0, 0);
    __builtin_amdgcn_global_load_lds((const __attribute__((address_space(1))) void*)(a1 + kt),
        (__attribute__((address_space(3))) void*)As1, 16, 0, 0);
    __builtin_amdgcn_global_load_lds((const __attribute__((address_space(1))) void*)(b0 + kt),
        (__attribute__((address_space(3))) void*)Bs0, 16, 0, 0);
    __builtin_amdgcn_global_load_lds((const __attribute__((address_space(1))) void*)(b1 + kt),
        (__attribute__((address_space(3))) void*)Bs1, 16, 0, 0);
    __syncthreads();
    bhalf8 af[4], bfr[4];
#pragma unroll
    for (int m=0;m<4;++m) af[m]  = *(const bhalf8*)(As + (wr*64 + m*16 + lrow)*32 + lk);
#pragma unroll
    for (int n=0;n<4;++n) bfr[n] = *(const bhalf8*)(Bs + (wc*64 + n*16 + lrow)*32 + lk);
#pragma unroll
    for (int m=0;m<4;++m)
#pragma unroll
      for (int n=0;n<4;++n)
        acc[m][n] = __builtin_amdgcn_mfma_f32_16x16x32_bf16(af[m], bfr[n], acc[m][n], 0, 0, 0);
    __syncthreads();
  }

#pragma unroll
  for (int m=0;m<4;++m){
    int rowb = m0 + wr*64 + m*16 + ((l>>4)<<2);
#pragma unroll
    for (int r=0;r<4;++r){
      size_t rbase = (size_t)(rowb + r)*N;
      size_t gbase = (size_t)(rowb + r)*gate_ld;
#pragma unroll
      for (int n=0;n<4;++n){
        int col = n0 + wc*64 + n*16 + (l&15);
        float v = acc[m][n][r];
        if (add) v += add[rbase + col];
        if (epi == 2) v *= sigmoidf_(gate[gbase + col]);
        C[rbase + col] = v;
      }
    }
  }
}

// ---------------- small f32 GEMM (kept for K=256 paths) -------------------------
// C[M,N] = A[M,K](lda) @ opB.  transb=1: B[N,K]; transb=0: B[K,N].
__global__ __launch_bounds__(256) void k_gemm(const float* __restrict__ A, int lda,
    const float* __restrict__ B, float* __restrict__ C, int M, int N, int K, int transb){
  __shared__ float Asm[16][64];
  __shared__ float Bsm[16][64];
  int tid = threadIdx.x;
  int bi = blockIdx.y, bj = blockIdx.x;
  int tx = tid & 15, ty = tid >> 4;
  int arow = tid >> 2, akq = (tid & 3) << 2;
  int bk = tid >> 4, bnq = (tid & 15) << 2;
  float acc[4][4] = {{0.f}};
  for (int kt = 0; kt < K; kt += 16){
    float4 av = *(const float4*)(A + (size_t)(bi*64 + arow)*lda + kt + akq);
    Asm[akq+0][arow]=av.x; Asm[akq+1][arow]=av.y; Asm[akq+2][arow]=av.z; Asm[akq+3][arow]=av.w;
    if (transb){
      float4 bv = *(const float4*)(B + (size_t)(bj*64 + arow)*K + kt + akq);
      Bsm[akq+0][arow]=bv.x; Bsm[akq+1][arow]=bv.y; Bsm[akq+2][arow]=bv.z; Bsm[akq+3][arow]=bv.w;
    } else {
      float4 bv = *(const float4*)(B + (size_t)(kt + bk)*N + bj*64 + bnq);
      Bsm[bk][bnq+0]=bv.x; Bsm[bk][bnq+1]=bv.y; Bsm[bk][bnq+2]=bv.z; Bsm[bk][bnq+3]=bv.w;
    }
    __syncthreads();
#pragma unroll
    for (int k = 0; k < 16; ++k){
      float a[4], b[4];
#pragma unroll
      for (int u = 0; u < 4; ++u) a[u] = Asm[k][ty*4+u];
#pragma unroll
      for (int u = 0; u < 4; ++u) b[u] = Bsm[k][tx*4+u];
#pragma unroll
      for (int i = 0; i < 4; ++i)
#pragma unroll
        for (int j = 0; j < 4; ++j) acc[i][j] = fmaf(a[i], b[j], acc[i][j]);
    }
    __syncthreads();
  }
#pragma unroll
  for (int i = 0; i < 4; ++i)
#pragma unroll
    for (int j = 0; j < 4; ++j)
      C[(size_t)(bi*64 + ty*4 + i)*N + bj*64 + tx*4 + j] = acc[i][j];
}

// ---------------- RoPE: Q (strided, in-place), K0 -> KA (pos 64+i), KB (pos i) --
__global__ void k_rope(float* __restrict__ Q, int qld, const float* __restrict__ K0,
                       float* __restrict__ KA, float* __restrict__ KB){
  int t = blockIdx.x, j = threadIdx.x;   // j in [0,128)
  int i = t & 63;
  float inv = powf(10000.f, -(float)(2*j)/256.f);
  float aa = (float)(i + 64)*inv;
  float ab = (float)i*inv;
  float ca = cosf(aa), sa = sinf(aa);
  float cb = cosf(ab), sb = sinf(ab);
  size_t qbase = (size_t)t*qld + 2*j;
  size_t kbase = (size_t)t*256 + 2*j;
  float q0 = Q[qbase], q1 = Q[qbase+1];
  Q[qbase]   = q0*ca - q1*sa;
  Q[qbase+1] = q1*ca + q0*sa;
  float k0 = K0[kbase], k1 = K0[kbase+1];
  KA[kbase]   = k0*ca - k1*sa;
  KA[kbase+1] = k1*ca + k0*sa;
  KB[kbase]   = k0*cb - k1*sb;
  KB[kbase+1] = k1*cb + k0*sb;
}

// ---------------- attention scores + softmax -> P[c][64][128] -------------------
__global__ __launch_bounds__(256) void k_attn_scores(const float* __restrict__ Q, int qld,
    const float* __restrict__ KA, const float* __restrict__ KB, float* __restrict__ P){
  __shared__ float S[64][128];
  int c = blockIdx.x, tid = threadIdx.x;
  for (int idx = tid; idx < 64*128; idx += 256){
    int i = idx >> 7, m = idx & 127;
    float s;
    if (m > i + 64){
      s = -INFINITY;
    } else if (m < 64 && c == 0){
      s = 0.f;
    } else {
      const float* qr = Q + (size_t)(c*64 + i)*qld;
      const float* kr = (m < 64) ? (KB + ((size_t)(c-1)*64 + m)*256)
                                 : (KA + ((size_t)c*64 + (m-64))*256);
      float acc = 0.f;
      for (int d = 0; d < 256; d += 4){
        float4 qv = *(const float4*)(qr + d);
        float4 kv = *(const float4*)(kr + d);
        acc += qv.x*kv.x + qv.y*kv.y + qv.z*kv.z + qv.w*kv.w;
      }
      s = acc * (1.f/16.f);
    }
    S[i][m] = s;
  }
  __syncthreads();
  if (tid < 64){
    int i = tid;
    float mx = -INFINITY;
    for (int m = 0; m < 128; ++m) mx = fmaxf(mx, S[i][m]);
    float sum = 0.f;
    for (int m = 0; m < 128; ++m){
      float v = S[i][m];
      float e = (v == -INFINITY) ? 0.f : expf(v - mx);
      S[i][m] = e; sum += e;
    }
    float r = 1.f/sum;
    float* pr = P + ((size_t)c*64 + i)*128;
    for (int m = 0; m < 128; ++m) pr[m] = S[i][m]*r;
  }
}

// ---------------- PV: Y[c*64+i,:] = sum_m P[c,i,m]*V2[c,m,:]  (V strided, Y bf16)
__global__ __launch_bounds__(256) void k_attn_pv(const float* __restrict__ P,
    const float* __restrict__ V, int vld, unsigned short* __restrict__ Y){
  __shared__ float Pl[64][128];
  __shared__ float Vt[128][64];
  int ct = blockIdx.x, c = blockIdx.y;
  int tid = threadIdx.x;
  for (int q = tid; q < 2048; q += 256)
    ((float4*)&Pl[0][0])[q] = ((const float4*)(P + (size_t)c*8192))[q];
  for (int q = tid; q < 2048; q += 256){
    int r = q >> 4, cq = (q & 15) << 2;
    float4 v;
    if (c == 0 && r < 64) v = make_float4(0.f,0.f,0.f,0.f);
    else {
      int gr = (c-1)*64 + r;
      v = *(const float4*)(V + (size_t)gr*vld + ct*64 + cq);
    }
    *(float4*)&Vt[r][cq] = v;
  }
  __syncthreads();
  int tx = tid & 15, ty = tid >> 4;
  float acc[4][4] = {{0.f}};
  for (int m = 0; m < 128; ++m){
    float a[4], b[4];
#pragma unroll
    for (int u=0;u<4;++u) a[u] = Pl[ty*4+u][m];
#pragma unroll
    for (int u=0;u<4;++u) b[u] = Vt[m][tx*4+u];
#pragma unroll
    for (int i=0;i<4;++i)
#pragma unroll
      for (int j=0;j<4;++j) acc[i][j] = fmaf(a[i], b[j], acc[i][j]);
  }
#pragma unroll
  for (int i=0;i<4;++i)
#pragma unroll
    for (int j=0;j<4;++j)
      Y[(size_t)(c*64 + ty*4 + i)*2048 + ct*64 + tx*4 + j] = f2b(acc[i][j]);
}

// ---------------- mem scan, 8 memories per block --------------------------------
__global__ __launch_bounds__(256) void k_scan1(const float* __restrict__ CC,
    const float* __restrict__ beta_p, const float* __restrict__ decay_p,
    float* __restrict__ CP, float* __restrict__ CQ){
  int c = blockIdx.x, mg = blockIdx.y, d = threadIdx.x;
  __shared__ float Fs[512];
  for (int v = threadIdx.x; v < 512; v += 256){
    int s = v >> 3, j = v & 7;
    Fs[v] = sigmoidf_(CC[(size_t)(c*64+s)*CC_LD + COL_FG + mg*8 + j]);
  }
  __syncthreads();
  float beta[8], gamma[8], Pa[8], Qa[8];
#pragma unroll
  for (int j=0;j<8;++j){
    int m = mg*8+j;
    beta[j]  = sigmoidf_(beta_p[m*256+d]);
    gamma[j] = (d < 192) ? 1.f : sigmoidf_(decay_p[m*64 + (d-192)]);
    Pa[j] = 1.f; Qa[j] = 0.f;
  }
  for (int s = 0; s < 64; ++s){
    float vm = CC[(size_t)(c*64+s)*CC_LD + COL_VM + d];
#pragma unroll
    for (int j=0;j<8;++j){
      float f = Fs[s*8+j];
      float w = (1.f - f*beta[j])*gamma[j];
      Pa[j] *= w;
      Qa[j] = w*Qa[j] + f*vm;
    }
  }
#pragma unroll
  for (int j=0;j<8;++j){
    size_t idx = ((size_t)c*64 + mg*8 + j)*256 + d;
    CP[idx] = Pa[j]; CQ[idx] = Qa[j];
  }
}

__global__ __launch_bounds__(256) void k_scan2(const float* __restrict__ CP,
    const float* __restrict__ CQ, float* __restrict__ SIN){
  int m = blockIdx.x, d = threadIdx.x;
  float S = 0.f;
  for (int c = 0; c < 32; ++c){
    size_t idx = ((size_t)c*64 + m)*256 + d;
    SIN[idx] = S;
    S = CP[idx]*S + CQ[idx];
  }
}

__global__ __launch_bounds__(256) void k_scan3(const float* __restrict__ CC,
    const float* __restrict__ beta_p, const float* __restrict__ decay_p,
    const float* __restrict__ SIN, unsigned short* __restrict__ MEMS){
  int c = blockIdx.x, mg = blockIdx.y, d = threadIdx.x;
  __shared__ float Fs[512];
  for (int v = threadIdx.x; v < 512; v += 256){
    int s = v >> 3, j = v & 7;
    Fs[v] = sigmoidf_(CC[(size_t)(c*64+s)*CC_LD + COL_FG + mg*8 + j]);
  }
  __syncthreads();
  float beta[8], gamma[8], S[8];
#pragma unroll
  for (int j=0;j<8;++j){
    int m = mg*8+j;
    beta[j]  = sigmoidf_(beta_p[m*256+d]);
    gamma[j] = (d < 192) ? 1.f : sigmoidf_(decay_p[m*64 + (d-192)]);
    S[j] = SIN[((size_t)c*64 + m)*256 + d];
  }
  for (int s = 0; s < 64; ++s){
    float vm = CC[(size_t)(c*64+s)*CC_LD + COL_VM + d];
    size_t tb = (size_t)(c*64+s)*64;
#pragma unroll
    for (int j=0;j<8;++j){
      float f = Fs[s*8+j];
      float w = (1.f - f*beta[j])*gamma[j];
      S[j] = w*S[j] + f*vm;
      MEMS[(tb + mg*8 + j)*256 + d] = f2b(S[j]);
    }
  }
}

// ---------------- mem readout (bf16 MEMS, strided QM) ---------------------------
__global__ __launch_bounds__(256) void k_memread(const unsigned short* __restrict__ MEMS,
    const float* __restrict__ QH, const float* __restrict__ QMs, int qm_ld,
    const float* __restrict__ L, unsigned short* __restrict__ YMb){
  int t = blockIdx.x, tid = threadIdx.x;
  int wave = tid >> 6, lane = tid & 63;
  __shared__ float anorm[64];
  const unsigned short* Mt = MEMS + (size_t)t*16384;
  float4 qh4 = *(const float4*)(QH + (size_t)t*256 + lane*4);
  const float* qmr = QMs + (size_t)t*qm_ld;
  float4 qm4 = *(const float4*)(qmr + lane*4);
  for (int mi = 0; mi < 16; ++mi){
    int m = wave*16 + mi;
    ushort4 su = *(const ushort4*)(Mt + m*256 + lane*4);
    float4 l4 = *(const float4*)(L + (size_t)m*256 + lane*4);
    float p = b2f(su.x)*qh4.x + b2f(su.y)*qh4.y + b2f(su.z)*qh4.z + b2f(su.w)*qh4.w
            + l4.x*qm4.x + l4.y*qm4.y + l4.z*qm4.z + l4.w*qm4.w;
#pragma unroll
    for (int off = 32; off > 0; off >>= 1) p += __shfl_down(p, off);
    if (lane == 0) anorm[m] = p * (1.f/16.f);
  }
  __syncthreads();
  if (tid == 0){
    float mx = -INFINITY;
    for (int i = 0; i < 64; ++i) mx = fmaxf(mx, anorm[i]);
    float sum = 0.f;
    for (int i = 0; i < 64; ++i){ float e = expf(anorm[i]-mx); anorm[i] = e; sum += e; }
    float r = 1.f/sum;
    for (int i = 0; i < 64; ++i) anorm[i] *= r;
  }
  __syncthreads();
  float acc = 0.f;
  for (int m = 0; m < 64; ++m) acc += anorm[m]*b2f(Mt[m*256 + tid]);
  YMb[(size_t)t*256 + tid] = f2b(acc);
}

// ---------------- elementwise ----------------------------------------------------
__global__ void k_add3(const float* __restrict__ a, const float* __restrict__ b,
                       const float* __restrict__ c, float* __restrict__ o, int n4){
  int i = blockIdx.x*256 + threadIdx.x;
  if (i < n4){
    float4 x = ((const float4*)a)[i], y = ((const float4*)b)[i], z = ((const float4*)c)[i];
    float4 r; r.x=x.x+y.x+z.x; r.y=x.y+y.y+z.y; r.z=x.z+y.z+z.z; r.w=x.w+y.w+z.w;
    ((float4*)o)[i] = r;
  }
}

// silu(h1)*h2 from concat H12 [2048][5632] -> bf16 H1b [2048][2816]
__global__ void k_silumul_b(const float* __restrict__ H12, unsigned short* __restrict__ H1b, int n4){
  int i = blockIdx.x*256 + threadIdx.x;
  if (i < n4){
    int r = i / 704, c4 = i % 704;
    const float4 a = *(const float4*)(H12 + (size_t)r*5632 + c4*4);
    const float4 b = *(const float4*)(H12 + (size_t)r*5632 + 2816 + c4*4);
    ushort4 o;
    o.x = f2b(a.x*sigmoidf_(a.x)*b.x);
    o.y = f2b(a.y*sigmoidf_(a.y)*b.y);
    o.z = f2b(a.z*sigmoidf_(a.z)*b.z);
    o.w = f2b(a.w*sigmoidf_(a.w)*b.w);
    ((ushort4*)H1b)[i] = o;
  }
}

// ---------------- launch ---------------------------------------------------------
extern "C" void kernel_launch(void* const* d_in, const int* in_sizes, int n_in,
                              void* d_out, int out_size, void* d_ws, size_t ws_size,
                              hipStream_t stream){
  const float* xs        = (const float*)d_in[0];
  const float* attn_q    = (const float*)d_in[1];
  const float* attn_k    = (const float*)d_in[2];
  const float* attn_v    = (const float*)d_in[3];
  const float* attn_o    = (const float*)d_in[4];
  const float* attn_r    = (const float*)d_in[5];
  const float* mem_f     = (const float*)d_in[6];
  const float* mem_q     = (const float*)d_in[7];
  const float* mem_k     = (const float*)d_in[8];
  const float* mem_v     = (const float*)d_in[9];
  const float* mem_o     = (const float*)d_in[10];
  const float* mem_r     = (const float*)d_in[11];
  const float* mem_beta  = (const float*)d_in[12];
  const float* mem_decay = (const float*)d_in[13];
  const float* mem_l     = (const float*)d_in[14];
  const float* ff1       = (const float*)d_in[15];
  const float* ff2       = (const float*)d_in[16];
  const float* ffo       = (const float*)d_in[17];
  const float* sn1       = (const float*)d_in[18];
  const float* sn2       = (const float*)d_in[19];
  float* out = (float*)d_out;
  float* W = (float*)d_ws;

  // ---- workspace layout (float offsets), peak ~255 MB with aliasing ----
  unsigned short* XNb  = (unsigned short*)(W + 0);          // 2048x2048 bf16
  unsigned short* WCAT = (unsigned short*)(W + 2097152);    // 7040x2048 bf16
  float*          CC   = W + 9306112;                       // 2048x7040 f32
  unsigned short* AOB  = (unsigned short*)(W + 23724032);   // attn_o bf16
  unsigned short* MOB  = (unsigned short*)(W + 25821184);   // mem_o bf16
  unsigned short* FFW  = (unsigned short*)(W + 26083328);   // [ff1;ff2] bf16
  unsigned short* FFOB = (unsigned short*)(W + 31850496);   // ffo bf16
  float*          K0   = W + 34734080;                      // 2048x256
  float*          KA   = W + 35258368;
  float*          KB   = W + 35782656;
  float*          P    = W + 36306944;                      // 32x64x128
  unsigned short* Ybb  = (unsigned short*)(W + 36569088);   // 2048x2048 bf16
  float*          B2f  = W + 38666240;                      // 2048x2048
  float*          XS2  = W + 42860544;                      // 2048x2048
  unsigned short* MEMSb= (unsigned short*)(W + 47054848);   // 2048x64x256 bf16
  // aliases (sequential liveness):
  float*          B1f  = W + 2097152;                       // over WCAT (dead after big GEMM)
  float*          CP   = K0;                                // over K0/KA/KB (dead after scores)
  float*          CQ   = KA;
  float*          SIN  = KB;
  float*          QH   = W + 36569088;                      // over Ybb (dead after attn_o GEMM)
  unsigned short* YMb  = (unsigned short*)(W + 36569088 + 524288);
  unsigned short* XN2b = MEMSb;                             // over MEMSb (dead after memread)
  unsigned short* H1b  = (unsigned short*)(W + 47054848 + 2097152);
  float*          H12  = CC;                                // over CC (dead after mem_o gate)

  dim3 blk(256);

  // ---- weight conversions (concat layouts) ----
  unsigned short* WCu = WCAT;
  k_f2b<<<dim3(4096), blk, 0, stream>>>(attn_v, WCu + 0,        1048576);
  k_f2b<<<dim3(4096), blk, 0, stream>>>(attn_r, WCu + 4194304,  1048576);
  k_f2b<<<dim3(4096), blk, 0, stream>>>(mem_r,  WCu + 8388608,  1048576);
  k_f2b<<<dim3(512),  blk, 0, stream>>>(attn_q, WCu + 12582912, 131072);
  k_f2b<<<dim3(512),  blk, 0, stream>>>(mem_v,  WCu + 13107200, 131072);
  k_f2b<<<dim3(512),  blk, 0, stream>>>(mem_q,  WCu + 13631488, 131072);
  k_f2b<<<dim3(128),  blk, 0, stream>>>(mem_f,  WCu + 14155776, 32768);
  hipMemsetAsync(WCu + 14286848, 0, 262144, stream);  // zero-pad rows 6976..7039
  k_f2b<<<dim3(4096), blk, 0, stream>>>(attn_o, AOB, 1048576);
  k_f2b<<<dim3(512),  blk, 0, stream>>>(mem_o,  MOB, 131072);
  k_f2b<<<dim3(5632), blk, 0, stream>>>(ff1, FFW + 0,       1441792);
  k_f2b<<<dim3(5632), blk, 0, stream>>>(ff2, FFW + 5767168, 1441792);
  k_f2b<<<dim3(5632), blk, 0, stream>>>(ffo, FFOB, 1441792);

  // ---- xn = scale_norm(xs, g1) -> bf16 ----
  k_scalenorm_b<<<dim3(2048), blk, 0, stream>>>(xs, sn1, XNb);

  // ---- BIG concat GEMM: CC = XNb @ WCAT^T  [2048 x 7040 x 2048] ----
  k_gemm_bf<<<dim3(55, 16), blk, 0, stream>>>(XNb, WCAT, CC, CC_LD, 2048, 0, nullptr, nullptr, 0);

  // ---- attention ----
  k_gemm<<<dim3(4, 32), blk, 0, stream>>>(CC + COL_QB, CC_LD, attn_k, K0, 2048, 256, 256, 1);
  k_rope<<<dim3(2048), dim3(128), 0, stream>>>(CC + COL_QB, CC_LD, K0, KA, KB);
  k_attn_scores<<<dim3(32), blk, 0, stream>>>(CC + COL_QB, CC_LD, KA, KB, P);
  k_attn_pv<<<dim3(32, 32), blk, 0, stream>>>(P, CC + COL_V, CC_LD, Ybb);
  // B1f = (Ybb @ attn_o^T) * sigmoid(CC[:,B1])
  k_gemm_bf<<<dim3(16, 16), blk, 0, stream>>>(Ybb, AOB, B1f, 2048, 2048, 2, nullptr, CC + COL_B1, CC_LD);

  // ---- memory branch ----
  k_scan1<<<dim3(32, 8), blk, 0, stream>>>(CC, mem_beta, mem_decay, CP, CQ);
  k_scan2<<<dim3(64), blk, 0, stream>>>(CP, CQ, SIN);
  k_scan3<<<dim3(32, 8), blk, 0, stream>>>(CC, mem_beta, mem_decay, SIN, MEMSb);
  k_gemm<<<dim3(4, 32), blk, 0, stream>>>(CC + COL_QM, CC_LD, mem_k, QH, 2048, 256, 256, 0);
  k_memread<<<dim3(2048), blk, 0, stream>>>(MEMSb, QH, CC + COL_QM, CC_LD, mem_l, YMb);
  // B2f = (YMb @ mem_o^T) * sigmoid(CC[:,B2])
  k_gemm_bf<<<dim3(16, 16), blk, 0, stream>>>(YMb, MOB, B2f, 2048, 256, 2, nullptr, CC + COL_B2, CC_LD);

  // xs2 = attn_out + mem_out + xs
  k_add3<<<dim3(4096), blk, 0, stream>>>(B1f, B2f, xs, XS2, 1048576);

  // ---- FF ----
  k_scalenorm_b<<<dim3(2048), blk, 0, stream>>>(XS2, sn2, XN2b);
  k_gemm_bf<<<dim3(44, 16), blk, 0, stream>>>(XN2b, FFW, H12, 5632, 2048, 0, nullptr, nullptr, 0);
  k_silumul_b<<<dim3(5632), blk, 0, stream>>>(H12, H1b, 1441792);
  // out = H1b @ ffo^T + XS2
  k_gemm_bf<<<dim3(16, 16), blk, 0, stream>>>(H1b, FFOB, out, 2048, 2816, 0, XS2, nullptr, 0);
}

// Round 3
// 637.887 us; speedup vs baseline: 4.7900x; 1.3707x over previous
//
#include <hip/hip_runtime.h>
#include <math.h>

// RAMEN layer. Round 3: MFMA attention (scores+softmax fused, MFMA PV),
// bf16 V path, trig table. T=2048, X_D=2048, M_D=256, M_N=64, CHUNK=64, FF_D=2816.

typedef short bhalf8 __attribute__((ext_vector_type(8)));
typedef float f32x4 __attribute__((ext_vector_type(4)));

#define CC_LD 4992
#define COL_B1  0
#define COL_B2  2048
#define COL_QB  4096
#define COL_VM  4352
#define COL_QM  4608
#define COL_FG  4864

__device__ __forceinline__ float sigmoidf_(float x){ return 1.0f/(1.0f+expf(-x)); }

__device__ __forceinline__ unsigned short f2b(float f){
  unsigned u = __float_as_uint(f);
  unsigned r = (u + 0x7fffu + ((u>>16)&1u)) >> 16;
  return (unsigned short)r;
}
__device__ __forceinline__ float b2f(unsigned short h){
  return __uint_as_float(((unsigned)h)<<16);
}

// ---------------- f32 -> bf16 convert -------------------------------------------
__global__ void k_f2b(const float* __restrict__ s, unsigned short* __restrict__ d, int n4){
  int i = blockIdx.x*256 + threadIdx.x;
  if (i < n4){
    float4 v = ((const float4*)s)[i];
    ushort4 o;
    o.x = f2b(v.x); o.y = f2b(v.y); o.z = f2b(v.z); o.w = f2b(v.w);
    ((ushort4*)d)[i] = o;
  }
}

// ---------------- trig table: TR[pos][j] = (cos, sin)(pos * 10000^-(j/128)) -----
__global__ void k_trig(float2* __restrict__ TR){
  int idx = blockIdx.x*256 + threadIdx.x;   // 16384
  int pos = idx >> 7, j = idx & 127;
  float inv = powf(10000.f, -(float)j/128.f);
  float a = (float)pos * inv;
  TR[idx] = make_float2(cosf(a), sinf(a));
}

// ---------------- scale norm -> bf16 --------------------------------------------
__global__ __launch_bounds__(256) void k_scalenorm_b(const float* __restrict__ x,
    const float* __restrict__ g, unsigned short* __restrict__ ob){
  int row = blockIdx.x, tid = threadIdx.x;
  const float* xr = x + (size_t)row*2048;
  float ss = 0.f;
  for (int j = tid; j < 2048; j += 256){ float v = xr[j]; ss += v*v; }
  __shared__ float red[256];
  red[tid] = ss; __syncthreads();
  for (int s = 128; s > 0; s >>= 1){ if (tid < s) red[tid] += red[tid+s]; __syncthreads(); }
  float scale = g[0] / (sqrtf(red[0]) + 1e-8f);
  unsigned short* orow = ob + (size_t)row*2048;
  for (int j4 = tid; j4 < 512; j4 += 256){
    float4 v = *(const float4*)(xr + j4*4);
    ushort4 o;
    o.x = f2b(v.x*scale); o.y = f2b(v.y*scale); o.z = f2b(v.z*scale); o.w = f2b(v.w*scale);
    ((ushort4*)orow)[j4] = o;
  }
}

// ---------------- bf16 MFMA GEMM: C[M,N] = A[M,K] @ B[N,K]^T --------------------
// 128x128 tile, BK=32, 4 waves. epi: 0 none; 2: v *= sigmoid(gate); 3: bf16 out to Cb.
__global__ __launch_bounds__(256) void k_gemm_bf(
    const unsigned short* __restrict__ A, const unsigned short* __restrict__ B,
    float* __restrict__ C, unsigned short* __restrict__ Cb, int N, int K, int epi,
    const float* __restrict__ add, const float* __restrict__ gate, int gate_ld){
  __shared__ unsigned short As[128*32];
  __shared__ unsigned short Bs[128*32];
  int tid = threadIdx.x;
  int w = tid >> 6, l = tid & 63;
  int bi = blockIdx.y, bj = blockIdx.x;
  int m0 = bi*128, n0 = bj*128;
  int wr = w >> 1, wc = w & 1;

  f32x4 acc[4][4];
#pragma unroll
  for (int i=0;i<4;++i)
#pragma unroll
    for (int j=0;j<4;++j){ f32x4 z = {0.f,0.f,0.f,0.f}; acc[i][j] = z; }

  int q0 = (w*2+0)*64 + l, q1 = (w*2+1)*64 + l;
  int ar0 = q0>>2, ac0 = (q0&3)*8;
  int ar1 = q1>>2, ac1 = (q1&3)*8;
  const unsigned short* a0 = A + (size_t)(m0+ar0)*K + ac0;
  const unsigned short* a1 = A + (size_t)(m0+ar1)*K + ac1;
  const unsigned short* b0 = B + (size_t)(n0+ar0)*K + ac0;
  const unsigned short* b1 = B + (size_t)(n0+ar1)*K + ac1;
  unsigned short* As0 = As + (w*2+0)*512;
  unsigned short* As1 = As + (w*2+1)*512;
  unsigned short* Bs0 = Bs + (w*2+0)*512;
  unsigned short* Bs1 = Bs + (w*2+1)*512;
  int lrow = l & 15, lk = (l>>4)*8;

  for (int kt = 0; kt < K; kt += 32){
    __builtin_amdgcn_global_load_lds((const __attribute__((address_space(1))) void*)(a0 + kt),
        (__attribute__((address_space(3))) void*)As0, 16, 0, 0);
    __builtin_amdgcn_global_load_lds((const __attribute__((address_space(1))) void*)(a1 + kt),
        (__attribute__((address_space(3))) void*)As1, 16, 0, 0);
    __builtin_amdgcn_global_load_lds((const __attribute__((address_space(1))) void*)(b0 + kt),
        (__attribute__((address_space(3))) void*)Bs0, 16, 0, 0);
    __builtin_amdgcn_global_load_lds((const __attribute__((address_space(1))) void*)(b1 + kt),
        (__attribute__((address_space(3))) void*)Bs1, 16, 0, 0);
    __syncthreads();
    bhalf8 af[4], bfr[4];
#pragma unroll
    for (int m=0;m<4;++m) af[m]  = *(const bhalf8*)(As + (wr*64 + m*16 + lrow)*32 + lk);
#pragma unroll
    for (int n=0;n<4;++n) bfr[n] = *(const bhalf8*)(Bs + (wc*64 + n*16 + lrow)*32 + lk);
#pragma unroll
    for (int m=0;m<4;++m)
#pragma unroll
      for (int n=0;n<4;++n)
        acc[m][n] = __builtin_amdgcn_mfma_f32_16x16x32_bf16(af[m], bfr[n], acc[m][n], 0, 0, 0);
    __syncthreads();
  }

#pragma unroll
  for (int m=0;m<4;++m){
    int rowb = m0 + wr*64 + m*16 + ((l>>4)<<2);
#pragma unroll
    for (int r=0;r<4;++r){
      size_t rbase = (size_t)(rowb + r)*N;
      size_t gbase = (size_t)(rowb + r)*gate_ld;
#pragma unroll
      for (int n=0;n<4;++n){
        int col = n0 + wc*64 + n*16 + (l&15);
        float v = acc[m][n][r];
        if (add) v += add[rbase + col];
        if (epi == 2) v *= sigmoidf_(gate[gbase + col]);
        if (epi == 3) Cb[rbase + col] = f2b(v);
        else          C[rbase + col] = v;
      }
    }
  }
}

// ---------------- small f32 GEMM (K=256 paths) ----------------------------------
__global__ __launch_bounds__(256) void k_gemm(const float* __restrict__ A, int lda,
    const float* __restrict__ B, float* __restrict__ C, int M, int N, int K, int transb){
  __shared__ float Asm[16][64];
  __shared__ float Bsm[16][64];
  int tid = threadIdx.x;
  int bi = blockIdx.y, bj = blockIdx.x;
  int tx = tid & 15, ty = tid >> 4;
  int arow = tid >> 2, akq = (tid & 3) << 2;
  int bk = tid >> 4, bnq = (tid & 15) << 2;
  float acc[4][4] = {{0.f}};
  for (int kt = 0; kt < K; kt += 16){
    float4 av = *(const float4*)(A + (size_t)(bi*64 + arow)*lda + kt + akq);
    Asm[akq+0][arow]=av.x; Asm[akq+1][arow]=av.y; Asm[akq+2][arow]=av.z; Asm[akq+3][arow]=av.w;
    if (transb){
      float4 bv = *(const float4*)(B + (size_t)(bj*64 + arow)*K + kt + akq);
      Bsm[akq+0][arow]=bv.x; Bsm[akq+1][arow]=bv.y; Bsm[akq+2][arow]=bv.z; Bsm[akq+3][arow]=bv.w;
    } else {
      float4 bv = *(const float4*)(B + (size_t)(kt + bk)*N + bj*64 + bnq);
      Bsm[bk][bnq+0]=bv.x; Bsm[bk][bnq+1]=bv.y; Bsm[bk][bnq+2]=bv.z; Bsm[bk][bnq+3]=bv.w;
    }
    __syncthreads();
#pragma unroll
    for (int k = 0; k < 16; ++k){
      float a[4], b[4];
#pragma unroll
      for (int u = 0; u < 4; ++u) a[u] = Asm[k][ty*4+u];
#pragma unroll
      for (int u = 0; u < 4; ++u) b[u] = Bsm[k][tx*4+u];
#pragma unroll
      for (int i = 0; i < 4; ++i)
#pragma unroll
        for (int j = 0; j < 4; ++j) acc[i][j] = fmaf(a[i], b[j], acc[i][j]);
    }
    __syncthreads();
  }
#pragma unroll
  for (int i = 0; i < 4; ++i)
#pragma unroll
    for (int j = 0; j < 4; ++j)
      C[(size_t)(bi*64 + ty*4 + i)*N + bj*64 + tx*4 + j] = acc[i][j];
}

// ---------------- fused attention scores+softmax (MFMA) -------------------------
// One block per chunk c. Stages roped K2 (128x256 bf16, XOR-swizzled) in LDS,
// Q frags loaded+roped from CC directly. Register softmax. Writes P bf16.
__global__ __launch_bounds__(256) void k_attn_scores_mfma(
    const float* __restrict__ CCq, const float* __restrict__ K0,
    const float2* __restrict__ TR, unsigned short* __restrict__ P){
  __shared__ unsigned short Ks[128*256];   // 64 KB
  int c = blockIdx.x, tid = threadIdx.x;
  // ---- stage roped K2 ----
  for (int it = 0; it < 16; ++it){
    int id = tid + it*256;          // 0..4095
    int m = id >> 5;                // key row 0..127, rope pos = m
    int cs = (id & 31) * 8;         // f32 col start
    float v[8];
    if (c == 0 && m < 64){
#pragma unroll
      for (int u=0;u<8;++u) v[u] = 0.f;
    } else {
      int gr = (c-1)*64 + m;
      const float* kr = K0 + (size_t)gr*256 + cs;
      float4 x0 = *(const float4*)kr, x1 = *(const float4*)(kr+4);
      v[0]=x0.x; v[1]=x0.y; v[2]=x0.z; v[3]=x0.w;
      v[4]=x1.x; v[5]=x1.y; v[6]=x1.z; v[7]=x1.w;
#pragma unroll
      for (int p2=0;p2<4;++p2){
        float2 t = TR[m*128 + (cs>>1) + p2];
        float e = v[2*p2], o = v[2*p2+1];
        v[2*p2]   = e*t.x - o*t.y;
        v[2*p2+1] = o*t.x + e*t.y;
      }
    }
    unsigned short pk[8];
#pragma unroll
    for (int u=0;u<8;++u) pk[u] = f2b(v[u]);
    int byte = m*512 + ((cs*2) ^ ((m&7)<<4));
    *(bhalf8*)((char*)&Ks[0] + byte) = *(const bhalf8*)pk;
  }
  __syncthreads();

  int w = tid >> 6, l = tid & 63;
  int lr = l & 15, lkg = l >> 4;    // 0..3
  f32x4 acc[8];
#pragma unroll
  for (int n=0;n<8;++n){ f32x4 z = {0.f,0.f,0.f,0.f}; acc[n] = z; }

  int iq = w*16 + lr;               // A-frag query row (0..63)
  const float* qbase = CCq + (size_t)(c*64 + iq)*CC_LD;
  int pos = 64 + iq;

  for (int kt = 0; kt < 8; ++kt){
    int k0c = kt*32 + lkg*8;
    const float* qp = qbase + k0c;
    float4 x0 = *(const float4*)qp, x1 = *(const float4*)(qp+4);
    float v[8];
    v[0]=x0.x; v[1]=x0.y; v[2]=x0.z; v[3]=x0.w;
    v[4]=x1.x; v[5]=x1.y; v[6]=x1.z; v[7]=x1.w;
#pragma unroll
    for (int p2=0;p2<4;++p2){
      float2 t = TR[pos*128 + (k0c>>1) + p2];
      float e = v[2*p2], o = v[2*p2+1];
      v[2*p2]   = e*t.x - o*t.y;
      v[2*p2+1] = o*t.x + e*t.y;
    }
    unsigned short pk[8];
#pragma unroll
    for (int u=0;u<8;++u) pk[u] = f2b(v[u]);
    bhalf8 af = *(const bhalf8*)pk;
#pragma unroll
    for (int n=0;n<8;++n){
      int m = n*16 + lr;
      int byte = m*512 + ((k0c*2) ^ ((m&7)<<4));
      bhalf8 bf = *(const bhalf8*)((const char*)&Ks[0] + byte);
      acc[n] = __builtin_amdgcn_mfma_f32_16x16x32_bf16(af, bf, acc[n], 0, 0, 0);
    }
  }

  // ---- register softmax (C-layout: col = n*16+lr, row = w*16 + lkg*4 + r) ----
  int i0 = w*16 + lkg*4;
  float mx[4] = {-1e30f,-1e30f,-1e30f,-1e30f};
  float sm[4] = {0.f,0.f,0.f,0.f};
#pragma unroll
  for (int n=0;n<8;++n){
    int col = n*16 + lr;
#pragma unroll
    for (int r=0;r<4;++r){
      float vv = acc[n][r] * (1.f/16.f);
      if (col > i0 + r + 64) vv = -1e30f;
      acc[n][r] = vv;
      mx[r] = fmaxf(mx[r], vv);
    }
  }
#pragma unroll
  for (int s=1; s<16; s<<=1)
#pragma unroll
    for (int r=0;r<4;++r) mx[r] = fmaxf(mx[r], __shfl_xor(mx[r], s));
#pragma unroll
  for (int n=0;n<8;++n)
#pragma unroll
    for (int r=0;r<4;++r){
      float e = expf(acc[n][r] - mx[r]);
      acc[n][r] = e; sm[r] += e;
    }
#pragma unroll
  for (int s=1; s<16; s<<=1)
#pragma unroll
    for (int r=0;r<4;++r) sm[r] += __shfl_xor(sm[r], s);
  float rcp[4];
#pragma unroll
  for (int r=0;r<4;++r) rcp[r] = 1.f/sm[r];

  unsigned short* Pr = P + (size_t)c*8192;
#pragma unroll
  for (int n=0;n<8;++n){
    int col = n*16 + lr;
#pragma unroll
    for (int r=0;r<4;++r)
      Pr[(i0+r)*128 + col] = f2b(acc[n][r]*rcp[r]);
  }
}

// ---------------- MFMA PV: Y[c*64+i, ct*128+:] = P[c] @ V2[c] -------------------
__global__ __launch_bounds__(256) void k_attn_pv_mfma(
    const unsigned short* __restrict__ P, const unsigned short* __restrict__ Vb,
    unsigned short* __restrict__ Y){
  __shared__ unsigned short Vt[128*128];   // [col][k] swizzled, 32 KB
  int ct = blockIdx.x, c = blockIdx.y, tid = threadIdx.x;
  // stage V2 tile transposed
  {
    int k = tid >> 1;               // V2 row 0..127
    int ch = (tid & 1) * 64;        // col half
    if (c == 0 && k < 64){
      for (int u=0; u<64; ++u){
        int col = ch + u;
        int byte = col*256 + ((k*2) ^ ((col&7)<<4));
        *(unsigned short*)((char*)&Vt[0] + byte) = 0;
      }
    } else {
      int gr = (c-1)*64 + k;
      const unsigned short* vr = Vb + (size_t)gr*2048 + ct*128 + ch;
      for (int u8=0; u8<8; ++u8){
        bhalf8 x = *(const bhalf8*)(vr + u8*8);
#pragma unroll
        for (int u=0;u<8;++u){
          int col = ch + u8*8 + u;
          int byte = col*256 + ((k*2) ^ ((col&7)<<4));
          *(unsigned short*)((char*)&Vt[0] + byte) = (unsigned short)(((short*)&x)[u]);
        }
      }
    }
  }
  __syncthreads();
  int w = tid >> 6, l = tid & 63, lr = l & 15, lkg = l >> 4;
  f32x4 acc[8];
#pragma unroll
  for (int n=0;n<8;++n){ f32x4 z = {0.f,0.f,0.f,0.f}; acc[n] = z; }
  const unsigned short* Pr = P + (size_t)c*8192;
  for (int kt=0; kt<4; ++kt){
    int kb = kt*32 + lkg*8;
    bhalf8 af = *(const bhalf8*)(Pr + (w*16 + lr)*128 + kb);
#pragma unroll
    for (int n=0;n<8;++n){
      int col = n*16 + lr;
      int byte = col*256 + ((kb*2) ^ ((col&7)<<4));
      bhalf8 bf = *(const bhalf8*)((const char*)&Vt[0] + byte);
      acc[n] = __builtin_amdgcn_mfma_f32_16x16x32_bf16(af, bf, acc[n], 0, 0, 0);
    }
  }
  int row0 = c*64 + w*16 + lkg*4;
#pragma unroll
  for (int n=0;n<8;++n){
    int col = ct*128 + n*16 + lr;
#pragma unroll
    for (int r=0;r<4;++r)
      Y[(size_t)(row0+r)*2048 + col] = f2b(acc[n][r]);
  }
}

// ---------------- mem scan, 8 memories per block --------------------------------
__global__ __launch_bounds__(256) void k_scan1(const float* __restrict__ CC,
    const float* __restrict__ beta_p, const float* __restrict__ decay_p,
    float* __restrict__ CP, float* __restrict__ CQ){
  int c = blockIdx.x, mg = blockIdx.y, d = threadIdx.x;
  __shared__ float Fs[512];
  for (int v = threadIdx.x; v < 512; v += 256){
    int s = v >> 3, j = v & 7;
    Fs[v] = sigmoidf_(CC[(size_t)(c*64+s)*CC_LD + COL_FG + mg*8 + j]);
  }
  __syncthreads();
  float beta[8], gamma[8], Pa[8], Qa[8];
#pragma unroll
  for (int j=0;j<8;++j){
    int m = mg*8+j;
    beta[j]  = sigmoidf_(beta_p[m*256+d]);
    gamma[j] = (d < 192) ? 1.f : sigmoidf_(decay_p[m*64 + (d-192)]);
    Pa[j] = 1.f; Qa[j] = 0.f;
  }
  for (int s = 0; s < 64; ++s){
    float vm = CC[(size_t)(c*64+s)*CC_LD + COL_VM + d];
#pragma unroll
    for (int j=0;j<8;++j){
      float f = Fs[s*8+j];
      float w = (1.f - f*beta[j])*gamma[j];
      Pa[j] *= w;
      Qa[j] = w*Qa[j] + f*vm;
    }
  }
#pragma unroll
  for (int j=0;j<8;++j){
    size_t idx = ((size_t)c*64 + mg*8 + j)*256 + d;
    CP[idx] = Pa[j]; CQ[idx] = Qa[j];
  }
}

__global__ __launch_bounds__(256) void k_scan2(const float* __restrict__ CP,
    const float* __restrict__ CQ, float* __restrict__ SIN){
  int m = blockIdx.x, d = threadIdx.x;
  float S = 0.f;
  for (int c = 0; c < 32; ++c){
    size_t idx = ((size_t)c*64 + m)*256 + d;
    SIN[idx] = S;
    S = CP[idx]*S + CQ[idx];
  }
}

__global__ __launch_bounds__(256) void k_scan3(const float* __restrict__ CC,
    const float* __restrict__ beta_p, const float* __restrict__ decay_p,
    const float* __restrict__ SIN, unsigned short* __restrict__ MEMS){
  int c = blockIdx.x, mg = blockIdx.y, d = threadIdx.x;
  __shared__ float Fs[512];
  for (int v = threadIdx.x; v < 512; v += 256){
    int s = v >> 3, j = v & 7;
    Fs[v] = sigmoidf_(CC[(size_t)(c*64+s)*CC_LD + COL_FG + mg*8 + j]);
  }
  __syncthreads();
  float beta[8], gamma[8], S[8];
#pragma unroll
  for (int j=0;j<8;++j){
    int m = mg*8+j;
    beta[j]  = sigmoidf_(beta_p[m*256+d]);
    gamma[j] = (d < 192) ? 1.f : sigmoidf_(decay_p[m*64 + (d-192)]);
    S[j] = SIN[((size_t)c*64 + m)*256 + d];
  }
  for (int s = 0; s < 64; ++s){
    float vm = CC[(size_t)(c*64+s)*CC_LD + COL_VM + d];
    size_t tb = (size_t)(c*64+s)*64;
#pragma unroll
    for (int j=0;j<8;++j){
      float f = Fs[s*8+j];
      float w = (1.f - f*beta[j])*gamma[j];
      S[j] = w*S[j] + f*vm;
      MEMS[(tb + mg*8 + j)*256 + d] = f2b(S[j]);
    }
  }
}

// ---------------- mem readout ----------------------------------------------------
__global__ __launch_bounds__(256) void k_memread(const unsigned short* __restrict__ MEMS,
    const float* __restrict__ QH, const float* __restrict__ QMs, int qm_ld,
    const float* __restrict__ L, unsigned short* __restrict__ YMb){
  int t = blockIdx.x, tid = threadIdx.x;
  int wave = tid >> 6, lane = tid & 63;
  __shared__ float anorm[64];
  const unsigned short* Mt = MEMS + (size_t)t*16384;
  float4 qh4 = *(const float4*)(QH + (size_t)t*256 + lane*4);
  const float* qmr = QMs + (size_t)t*qm_ld;
  float4 qm4 = *(const float4*)(qmr + lane*4);
  for (int mi = 0; mi < 16; ++mi){
    int m = wave*16 + mi;
    ushort4 su = *(const ushort4*)(Mt + m*256 + lane*4);
    float4 l4 = *(const float4*)(L + (size_t)m*256 + lane*4);
    float p = b2f(su.x)*qh4.x + b2f(su.y)*qh4.y + b2f(su.z)*qh4.z + b2f(su.w)*qh4.w
            + l4.x*qm4.x + l4.y*qm4.y + l4.z*qm4.z + l4.w*qm4.w;
#pragma unroll
    for (int off = 32; off > 0; off >>= 1) p += __shfl_down(p, off);
    if (lane == 0) anorm[m] = p * (1.f/16.f);
  }
  __syncthreads();
  if (tid == 0){
    float mx = -INFINITY;
    for (int i = 0; i < 64; ++i) mx = fmaxf(mx, anorm[i]);
    float sum = 0.f;
    for (int i = 0; i < 64; ++i){ float e = expf(anorm[i]-mx); anorm[i] = e; sum += e; }
    float r = 1.f/sum;
    for (int i = 0; i < 64; ++i) anorm[i] *= r;
  }
  __syncthreads();
  float acc = 0.f;
  for (int m = 0; m < 64; ++m) acc += anorm[m]*b2f(Mt[m*256 + tid]);
  YMb[(size_t)t*256 + tid] = f2b(acc);
}

// ---------------- elementwise ----------------------------------------------------
__global__ void k_add3(const float* __restrict__ a, const float* __restrict__ b,
                       const float* __restrict__ c, float* __restrict__ o, int n4){
  int i = blockIdx.x*256 + threadIdx.x;
  if (i < n4){
    float4 x = ((const float4*)a)[i], y = ((const float4*)b)[i], z = ((const float4*)c)[i];
    float4 r; r.x=x.x+y.x+z.x; r.y=x.y+y.y+z.y; r.z=x.z+y.z+z.z; r.w=x.w+y.w+z.w;
    ((float4*)o)[i] = r;
  }
}

__global__ void k_silumul_b(const float* __restrict__ H12, unsigned short* __restrict__ H1b, int n4){
  int i = blockIdx.x*256 + threadIdx.x;
  if (i < n4){
    int r = i / 704, c4 = i % 704;
    const float4 a = *(const float4*)(H12 + (size_t)r*5632 + c4*4);
    const float4 b = *(const float4*)(H12 + (size_t)r*5632 + 2816 + c4*4);
    ushort4 o;
    o.x = f2b(a.x*sigmoidf_(a.x)*b.x);
    o.y = f2b(a.y*sigmoidf_(a.y)*b.y);
    o.z = f2b(a.z*sigmoidf_(a.z)*b.z);
    o.w = f2b(a.w*sigmoidf_(a.w)*b.w);
    ((ushort4*)H1b)[i] = o;
  }
}

// ---------------- launch ---------------------------------------------------------
extern "C" void kernel_launch(void* const* d_in, const int* in_sizes, int n_in,
                              void* d_out, int out_size, void* d_ws, size_t ws_size,
                              hipStream_t stream){
  const float* xs        = (const float*)d_in[0];
  const float* attn_q    = (const float*)d_in[1];
  const float* attn_k    = (const float*)d_in[2];
  const float* attn_v    = (const float*)d_in[3];
  const float* attn_o    = (const float*)d_in[4];
  const float* attn_r    = (const float*)d_in[5];
  const float* mem_f     = (const float*)d_in[6];
  const float* mem_q     = (const float*)d_in[7];
  const float* mem_k     = (const float*)d_in[8];
  const float* mem_v     = (const float*)d_in[9];
  const float* mem_o     = (const float*)d_in[10];
  const float* mem_r     = (const float*)d_in[11];
  const float* mem_beta  = (const float*)d_in[12];
  const float* mem_decay = (const float*)d_in[13];
  const float* mem_l     = (const float*)d_in[14];
  const float* ff1       = (const float*)d_in[15];
  const float* ff2       = (const float*)d_in[16];
  const float* ffo       = (const float*)d_in[17];
  const float* sn1       = (const float*)d_in[18];
  const float* sn2       = (const float*)d_in[19];
  float* out = (float*)d_out;
  float* W = (float*)d_ws;

  // ---- workspace layout (float offsets), ~251 MB with aliasing ----
  unsigned short* XNb  = (unsigned short*)(W + 0);           // 2,097,152 fl
  unsigned short* AVB  = (unsigned short*)(W + 2097152);     // 2,097,152 fl (attn_v bf16)
  unsigned short* WC2  = (unsigned short*)(W + 4194304);     // 5,111,808 fl (4992x2048 bf16)
  unsigned short* Vb   = (unsigned short*)(W + 9306112);     // 2,097,152 fl
  float*          CC   = W + 11403264;                       // 10,223,616 fl (2048x4992)
  unsigned short* AOB  = (unsigned short*)(W + 22937600);    // 2,097,152 fl
  unsigned short* MOB  = (unsigned short*)(W + 25034752);    // 262,144 fl
  unsigned short* FFW  = (unsigned short*)(W + 25296896);    // 5,767,168 fl
  unsigned short* FFOB = (unsigned short*)(W + 31064064);    // 2,883,584 fl
  unsigned short* Ybb  = (unsigned short*)(W + 33947648);    // 2,097,152 fl
  float*          B2f  = W + 36044800;                       // 4,194,304 fl
  float*          XS2  = W + 40239104;                       // 4,194,304 fl
  unsigned short* MEMSb= (unsigned short*)(W + 44433408);    // 16,777,216 fl
  float*          CP   = W + 61210624;                       // 524,288 fl
  float*          CQ   = W + 61734912;                       // 524,288 fl
  float*          SIN  = W + 62259200;                       // 524,288 fl
  // aliases (sequential liveness):
  float2*         TRIG = (float2*)(W + 0);                   // over XNb, 32,768 fl
  float*          K0   = W + 32768;                          // over XNb, 524,288 fl
  unsigned short* P    = (unsigned short*)(W + 557056);      // over XNb, 131,072 fl
  float*          QH   = W + 688128;                         // over XNb, 524,288 fl
  unsigned short* YMb  = (unsigned short*)(W + 1212416);     // over XNb, 262,144 fl
  float*          B1f  = W + 2097152;                        // over AVB+WC2 head
  unsigned short* XN2b = MEMSb;                              // over MEMSb
  unsigned short* H1b  = (unsigned short*)(W + 46530560);    // over MEMSb tail
  float*          H12  = CC;                                 // over CC (extends past; ends 22,937,600)

  dim3 blk(256);

  // ---- weight conversions ----
  unsigned short* WCu = WC2;
  k_f2b<<<dim3(4096), blk, 0, stream>>>(attn_v, (unsigned short*)AVB, 1048576);
  k_f2b<<<dim3(4096), blk, 0, stream>>>(attn_r, WCu + 0,       1048576);
  k_f2b<<<dim3(4096), blk, 0, stream>>>(mem_r,  WCu + 4194304, 1048576);
  k_f2b<<<dim3(512),  blk, 0, stream>>>(attn_q, WCu + 8388608, 131072);
  k_f2b<<<dim3(512),  blk, 0, stream>>>(mem_v,  WCu + 8912896, 131072);
  k_f2b<<<dim3(512),  blk, 0, stream>>>(mem_q,  WCu + 9437184, 131072);
  k_f2b<<<dim3(128),  blk, 0, stream>>>(mem_f,  WCu + 9961472, 32768);
  hipMemsetAsync(WCu + 10092544, 0, 262144, stream);   // pad rows 4928..4991
  k_f2b<<<dim3(4096), blk, 0, stream>>>(attn_o, AOB, 1048576);
  k_f2b<<<dim3(512),  blk, 0, stream>>>(mem_o,  MOB, 131072);
  k_f2b<<<dim3(5632), blk, 0, stream>>>(ff1, FFW + 0,       1441792);
  k_f2b<<<dim3(5632), blk, 0, stream>>>(ff2, FFW + 5767168, 1441792);
  k_f2b<<<dim3(5632), blk, 0, stream>>>(ffo, FFOB, 1441792);

  // ---- xn = scale_norm(xs, g1) -> bf16 ----
  k_scalenorm_b<<<dim3(2048), blk, 0, stream>>>(xs, sn1, XNb);

  // ---- V (bf16 out) + concat CC GEMMs ----
  k_gemm_bf<<<dim3(16, 16), blk, 0, stream>>>(XNb, AVB, nullptr, Vb, 2048, 2048, 3, nullptr, nullptr, 0);
  k_gemm_bf<<<dim3(39, 16), blk, 0, stream>>>(XNb, WC2, CC, nullptr, CC_LD, 2048, 0, nullptr, nullptr, 0);

  // ---- trig table (XNb region now dead) ----
  k_trig<<<dim3(64), blk, 0, stream>>>(TRIG);

  // ---- attention ----
  k_gemm<<<dim3(4, 32), blk, 0, stream>>>(CC + COL_QB, CC_LD, attn_k, K0, 2048, 256, 256, 1);
  k_attn_scores_mfma<<<dim3(32), blk, 0, stream>>>(CC + COL_QB, K0, TRIG, P);
  k_attn_pv_mfma<<<dim3(16, 32), blk, 0, stream>>>(P, Vb, Ybb);
  k_gemm_bf<<<dim3(16, 16), blk, 0, stream>>>(Ybb, AOB, B1f, nullptr, 2048, 2048, 2, nullptr, CC + COL_B1, CC_LD);

  // ---- memory branch ----
  k_scan1<<<dim3(32, 8), blk, 0, stream>>>(CC, mem_beta, mem_decay, CP, CQ);
  k_scan2<<<dim3(64), blk, 0, stream>>>(CP, CQ, SIN);
  k_scan3<<<dim3(32, 8), blk, 0, stream>>>(CC, mem_beta, mem_decay, SIN, MEMSb);
  k_gemm<<<dim3(4, 32), blk, 0, stream>>>(CC + COL_QM, CC_LD, mem_k, QH, 2048, 256, 256, 0);
  k_memread<<<dim3(2048), blk, 0, stream>>>(MEMSb, QH, CC + COL_QM, CC_LD, mem_l, YMb);
  k_gemm_bf<<<dim3(16, 16), blk, 0, stream>>>(YMb, MOB, B2f, nullptr, 2048, 256, 2, nullptr, CC + COL_B2, CC_LD);

  // xs2 = attn_out + mem_out + xs
  k_add3<<<dim3(4096), blk, 0, stream>>>(B1f, B2f, xs, XS2, 1048576);

  // ---- FF ----
  k_scalenorm_b<<<dim3(2048), blk, 0, stream>>>(XS2, sn2, XN2b);
  k_gemm_bf<<<dim3(44, 16), blk, 0, stream>>>(XN2b, FFW, H12, nullptr, 5632, 2048, 0, nullptr, nullptr, 0);
  k_silumul_b<<<dim3(5632), blk, 0, stream>>>(H12, H1b, 1441792);
  k_gemm_bf<<<dim3(16, 16), blk, 0, stream>>>(H1b, FFOB, out, nullptr, 2048, 2816, 0, XS2, nullptr, 0);
}

// Round 4
// 589.532 us; speedup vs baseline: 5.1829x; 1.0820x over previous
//
#include <hip/hip_runtime.h>
#include <math.h>

// RAMEN layer. Round 4: BN=64 GEMM tiles (2-5 blocks/CU), bf16 concat output CC,
// all GEMMs on MFMA. T=2048, X_D=2048, M_D=256, M_N=64, CHUNK=64, FF_D=2816.

typedef short bhalf8 __attribute__((ext_vector_type(8)));
typedef float f32x4 __attribute__((ext_vector_type(4)));

#define CC_LD 4992
#define COL_B1  0
#define COL_B2  2048
#define COL_QB  4096
#define COL_VM  4352
#define COL_QM  4608
#define COL_FG  4864

__device__ __forceinline__ float sigmoidf_(float x){ return 1.0f/(1.0f+expf(-x)); }

__device__ __forceinline__ unsigned short f2b(float f){
  unsigned u = __float_as_uint(f);
  unsigned r = (u + 0x7fffu + ((u>>16)&1u)) >> 16;
  return (unsigned short)r;
}
__device__ __forceinline__ float b2f(unsigned short h){
  return __uint_as_float(((unsigned)h)<<16);
}

// ---------------- f32 -> bf16 convert -------------------------------------------
__global__ void k_f2b(const float* __restrict__ s, unsigned short* __restrict__ d, int n4){
  int i = blockIdx.x*256 + threadIdx.x;
  if (i < n4){
    float4 v = ((const float4*)s)[i];
    ushort4 o;
    o.x = f2b(v.x); o.y = f2b(v.y); o.z = f2b(v.z); o.w = f2b(v.w);
    ((ushort4*)d)[i] = o;
  }
}

// transpose + convert for 256x256 (mem_k): d[n][k] = s[k][n]
__global__ void k_f2bT(const float* __restrict__ s, unsigned short* __restrict__ d){
  int i = blockIdx.x, j = threadIdx.x;
  d[(size_t)j*256 + i] = f2b(s[(size_t)i*256 + j]);
}

// ---------------- trig table: TR[pos][j] = (cos, sin)(pos * 10000^-(j/128)) -----
__global__ void k_trig(float2* __restrict__ TR){
  int idx = blockIdx.x*256 + threadIdx.x;   // 16384
  int pos = idx >> 7, j = idx & 127;
  float inv = powf(10000.f, -(float)j/128.f);
  float a = (float)pos * inv;
  TR[idx] = make_float2(cosf(a), sinf(a));
}

// ---------------- scale norm -> bf16 --------------------------------------------
__global__ __launch_bounds__(256) void k_scalenorm_b(const float* __restrict__ x,
    const float* __restrict__ g, unsigned short* __restrict__ ob){
  int row = blockIdx.x, tid = threadIdx.x;
  const float* xr = x + (size_t)row*2048;
  float ss = 0.f;
  for (int j = tid; j < 2048; j += 256){ float v = xr[j]; ss += v*v; }
  __shared__ float red[256];
  red[tid] = ss; __syncthreads();
  for (int s = 128; s > 0; s >>= 1){ if (tid < s) red[tid] += red[tid+s]; __syncthreads(); }
  float scale = g[0] / (sqrtf(red[0]) + 1e-8f);
  unsigned short* orow = ob + (size_t)row*2048;
  for (int j4 = tid; j4 < 512; j4 += 256){
    float4 v = *(const float4*)(xr + j4*4);
    ushort4 o;
    o.x = f2b(v.x*scale); o.y = f2b(v.y*scale); o.z = f2b(v.z*scale); o.w = f2b(v.w*scale);
    ((ushort4*)orow)[j4] = o;
  }
}

// ---------------- bf16 MFMA GEMM v2: C[M,N] = A[M,K](lda) @ B[N,K]^T ------------
// 128x64 tile, BK=32, 4 waves (2x2: 64x32 each). Grid (N/64, M/128).
// epi: 0 -> C f32 (+add); 2 -> C f32 * sigmoid(bf16 gate); 3 -> Cb bf16.
__global__ __launch_bounds__(256) void k_gemm_bf2(
    const unsigned short* __restrict__ A, int lda,
    const unsigned short* __restrict__ B,
    float* __restrict__ C, unsigned short* __restrict__ Cb,
    int N, int K, int ldc, int epi,
    const float* __restrict__ add,
    const unsigned short* __restrict__ gate, int gate_ld){
  __shared__ unsigned short As[128*32];   // 8 KB
  __shared__ unsigned short Bs[64*32];    // 4 KB
  int tid = threadIdx.x;
  int w = tid >> 6, l = tid & 63;
  int bi = blockIdx.y, bj = blockIdx.x;
  int m0 = bi*128, n0 = bj*64;
  int wr = w >> 1, wc = w & 1;

  f32x4 acc[4][2];
#pragma unroll
  for (int i=0;i<4;++i)
#pragma unroll
    for (int j=0;j<2;++j){ f32x4 z = {0.f,0.f,0.f,0.f}; acc[i][j] = z; }

  int qa0 = (w*2+0)*64 + l, qa1 = (w*2+1)*64 + l, qb = w*64 + l;
  const unsigned short* a0 = A + (size_t)(m0 + (qa0>>2))*lda + (qa0&3)*8;
  const unsigned short* a1 = A + (size_t)(m0 + (qa1>>2))*lda + (qa1&3)*8;
  const unsigned short* b0 = B + (size_t)(n0 + (qb>>2))*K + (qb&3)*8;
  unsigned short* As0 = As + (w*2+0)*512;
  unsigned short* As1 = As + (w*2+1)*512;
  unsigned short* Bs0 = Bs + w*512;
  int lrow = l & 15, lk = (l>>4)*8;

  for (int kt = 0; kt < K; kt += 32){
    __builtin_amdgcn_global_load_lds((const __attribute__((address_space(1))) void*)(a0 + kt),
        (__attribute__((address_space(3))) void*)As0, 16, 0, 0);
    __builtin_amdgcn_global_load_lds((const __attribute__((address_space(1))) void*)(a1 + kt),
        (__attribute__((address_space(3))) void*)As1, 16, 0, 0);
    __builtin_amdgcn_global_load_lds((const __attribute__((address_space(1))) void*)(b0 + kt),
        (__attribute__((address_space(3))) void*)Bs0, 16, 0, 0);
    __syncthreads();
    bhalf8 af[4], bfr[2];
#pragma unroll
    for (int m=0;m<4;++m) af[m]  = *(const bhalf8*)(As + (wr*64 + m*16 + lrow)*32 + lk);
#pragma unroll
    for (int n=0;n<2;++n) bfr[n] = *(const bhalf8*)(Bs + (wc*32 + n*16 + lrow)*32 + lk);
#pragma unroll
    for (int m=0;m<4;++m)
#pragma unroll
      for (int n=0;n<2;++n)
        acc[m][n] = __builtin_amdgcn_mfma_f32_16x16x32_bf16(af[m], bfr[n], acc[m][n], 0, 0, 0);
    __syncthreads();
  }

#pragma unroll
  for (int m=0;m<4;++m){
    int rowb = m0 + wr*64 + m*16 + ((l>>4)<<2);
#pragma unroll
    for (int r=0;r<4;++r){
      int row = rowb + r;
      size_t rbase = (size_t)row*ldc;
      size_t gbase = (size_t)row*gate_ld;
#pragma unroll
      for (int n=0;n<2;++n){
        int col = n0 + wc*32 + n*16 + (l&15);
        float v = acc[m][n][r];
        if (add) v += add[rbase + col];
        if (epi == 2) v *= sigmoidf_(b2f(gate[gbase + col]));
        if (epi == 3) Cb[rbase + col] = f2b(v);
        else          C[rbase + col] = v;
      }
    }
  }
}

// ---------------- fused attention scores+softmax (MFMA) -------------------------
// One block per chunk c. Stages roped K2 (128x256 bf16, XOR-swizzled) in LDS,
// Q frags loaded (bf16) + roped from CC directly. Register softmax. Writes P bf16.
__global__ __launch_bounds__(256) void k_attn_scores_mfma(
    const unsigned short* __restrict__ CCqb, const float* __restrict__ K0,
    const float2* __restrict__ TR, unsigned short* __restrict__ P){
  __shared__ unsigned short Ks[128*256];   // 64 KB
  int c = blockIdx.x, tid = threadIdx.x;
  // ---- stage roped K2 ----
  for (int it = 0; it < 16; ++it){
    int id = tid + it*256;          // 0..4095
    int m = id >> 5;                // key row 0..127, rope pos = m
    int cs = (id & 31) * 8;         // f32 col start
    float v[8];
    if (c == 0 && m < 64){
#pragma unroll
      for (int u=0;u<8;++u) v[u] = 0.f;
    } else {
      int gr = (c-1)*64 + m;
      const float* kr = K0 + (size_t)gr*256 + cs;
      float4 x0 = *(const float4*)kr, x1 = *(const float4*)(kr+4);
      v[0]=x0.x; v[1]=x0.y; v[2]=x0.z; v[3]=x0.w;
      v[4]=x1.x; v[5]=x1.y; v[6]=x1.z; v[7]=x1.w;
#pragma unroll
      for (int p2=0;p2<4;++p2){
        float2 t = TR[m*128 + (cs>>1) + p2];
        float e = v[2*p2], o = v[2*p2+1];
        v[2*p2]   = e*t.x - o*t.y;
        v[2*p2+1] = o*t.x + e*t.y;
      }
    }
    unsigned short pk[8];
#pragma unroll
    for (int u=0;u<8;++u) pk[u] = f2b(v[u]);
    int byte = m*512 + ((cs*2) ^ ((m&7)<<4));
    *(bhalf8*)((char*)&Ks[0] + byte) = *(const bhalf8*)pk;
  }
  __syncthreads();

  int w = tid >> 6, l = tid & 63;
  int lr = l & 15, lkg = l >> 4;    // 0..3
  f32x4 acc[8];
#pragma unroll
  for (int n=0;n<8;++n){ f32x4 z = {0.f,0.f,0.f,0.f}; acc[n] = z; }

  int iq = w*16 + lr;               // A-frag query row (0..63)
  const unsigned short* qbase = CCqb + (size_t)(c*64 + iq)*CC_LD;
  int pos = 64 + iq;

  for (int kt = 0; kt < 8; ++kt){
    int k0c = kt*32 + lkg*8;
    bhalf8 q8 = *(const bhalf8*)(qbase + k0c);
    float v[8];
#pragma unroll
    for (int u=0;u<8;++u) v[u] = b2f((unsigned short)(((short*)&q8)[u]));
#pragma unroll
    for (int p2=0;p2<4;++p2){
      float2 t = TR[pos*128 + (k0c>>1) + p2];
      float e = v[2*p2], o = v[2*p2+1];
      v[2*p2]   = e*t.x - o*t.y;
      v[2*p2+1] = o*t.x + e*t.y;
    }
    unsigned short pk[8];
#pragma unroll
    for (int u=0;u<8;++u) pk[u] = f2b(v[u]);
    bhalf8 af = *(const bhalf8*)pk;
#pragma unroll
    for (int n=0;n<8;++n){
      int m = n*16 + lr;
      int byte = m*512 + ((k0c*2) ^ ((m&7)<<4));
      bhalf8 bf = *(const bhalf8*)((const char*)&Ks[0] + byte);
      acc[n] = __builtin_amdgcn_mfma_f32_16x16x32_bf16(af, bf, acc[n], 0, 0, 0);
    }
  }

  // ---- register softmax (C-layout: col = n*16+lr, row = w*16 + lkg*4 + r) ----
  int i0 = w*16 + lkg*4;
  float mx[4] = {-1e30f,-1e30f,-1e30f,-1e30f};
  float sm[4] = {0.f,0.f,0.f,0.f};
#pragma unroll
  for (int n=0;n<8;++n){
    int col = n*16 + lr;
#pragma unroll
    for (int r=0;r<4;++r){
      float vv = acc[n][r] * (1.f/16.f);
      if (col > i0 + r + 64) vv = -1e30f;
      acc[n][r] = vv;
      mx[r] = fmaxf(mx[r], vv);
    }
  }
#pragma unroll
  for (int s=1; s<16; s<<=1)
#pragma unroll
    for (int r=0;r<4;++r) mx[r] = fmaxf(mx[r], __shfl_xor(mx[r], s));
#pragma unroll
  for (int n=0;n<8;++n)
#pragma unroll
    for (int r=0;r<4;++r){
      float e = expf(acc[n][r] - mx[r]);
      acc[n][r] = e; sm[r] += e;
    }
#pragma unroll
  for (int s=1; s<16; s<<=1)
#pragma unroll
    for (int r=0;r<4;++r) sm[r] += __shfl_xor(sm[r], s);
  float rcp[4];
#pragma unroll
  for (int r=0;r<4;++r) rcp[r] = 1.f/sm[r];

  unsigned short* Pr = P + (size_t)c*8192;
#pragma unroll
  for (int n=0;n<8;++n){
    int col = n*16 + lr;
#pragma unroll
    for (int r=0;r<4;++r)
      Pr[(i0+r)*128 + col] = f2b(acc[n][r]*rcp[r]);
  }
}

// ---------------- MFMA PV: Y[c*64+i, ct*128+:] = P[c] @ V2[c] -------------------
__global__ __launch_bounds__(256) void k_attn_pv_mfma(
    const unsigned short* __restrict__ P, const unsigned short* __restrict__ Vb,
    unsigned short* __restrict__ Y){
  __shared__ unsigned short Vt[128*128];   // [col][k] swizzled, 32 KB
  int ct = blockIdx.x, c = blockIdx.y, tid = threadIdx.x;
  {
    int k = tid >> 1;               // V2 row 0..127
    int ch = (tid & 1) * 64;        // col half
    if (c == 0 && k < 64){
      for (int u=0; u<64; ++u){
        int col = ch + u;
        int byte = col*256 + ((k*2) ^ ((col&7)<<4));
        *(unsigned short*)((char*)&Vt[0] + byte) = 0;
      }
    } else {
      int gr = (c-1)*64 + k;
      const unsigned short* vr = Vb + (size_t)gr*2048 + ct*128 + ch;
      for (int u8=0; u8<8; ++u8){
        bhalf8 x = *(const bhalf8*)(vr + u8*8);
#pragma unroll
        for (int u=0;u<8;++u){
          int col = ch + u8*8 + u;
          int byte = col*256 + ((k*2) ^ ((col&7)<<4));
          *(unsigned short*)((char*)&Vt[0] + byte) = (unsigned short)(((short*)&x)[u]);
        }
      }
    }
  }
  __syncthreads();
  int w = tid >> 6, l = tid & 63, lr = l & 15, lkg = l >> 4;
  f32x4 acc[8];
#pragma unroll
  for (int n=0;n<8;++n){ f32x4 z = {0.f,0.f,0.f,0.f}; acc[n] = z; }
  const unsigned short* Pr = P + (size_t)c*8192;
  for (int kt=0; kt<4; ++kt){
    int kb = kt*32 + lkg*8;
    bhalf8 af = *(const bhalf8*)(Pr + (w*16 + lr)*128 + kb);
#pragma unroll
    for (int n=0;n<8;++n){
      int col = n*16 + lr;
      int byte = col*256 + ((kb*2) ^ ((col&7)<<4));
      bhalf8 bf = *(const bhalf8*)((const char*)&Vt[0] + byte);
      acc[n] = __builtin_amdgcn_mfma_f32_16x16x32_bf16(af, bf, acc[n], 0, 0, 0);
    }
  }
  int row0 = c*64 + w*16 + lkg*4;
#pragma unroll
  for (int n=0;n<8;++n){
    int col = ct*128 + n*16 + lr;
#pragma unroll
    for (int r=0;r<4;++r)
      Y[(size_t)(row0+r)*2048 + col] = f2b(acc[n][r]);
  }
}

// ---------------- mem scan, 8 memories per block (CC bf16) ----------------------
__global__ __launch_bounds__(256) void k_scan1(const unsigned short* __restrict__ CC,
    const float* __restrict__ beta_p, const float* __restrict__ decay_p,
    float* __restrict__ CP, float* __restrict__ CQ){
  int c = blockIdx.x, mg = blockIdx.y, d = threadIdx.x;
  __shared__ float Fs[512];
  for (int v = threadIdx.x; v < 512; v += 256){
    int s = v >> 3, j = v & 7;
    Fs[v] = sigmoidf_(b2f(CC[(size_t)(c*64+s)*CC_LD + COL_FG + mg*8 + j]));
  }
  __syncthreads();
  float beta[8], gamma[8], Pa[8], Qa[8];
#pragma unroll
  for (int j=0;j<8;++j){
    int m = mg*8+j;
    beta[j]  = sigmoidf_(beta_p[m*256+d]);
    gamma[j] = (d < 192) ? 1.f : sigmoidf_(decay_p[m*64 + (d-192)]);
    Pa[j] = 1.f; Qa[j] = 0.f;
  }
  for (int s = 0; s < 64; ++s){
    float vm = b2f(CC[(size_t)(c*64+s)*CC_LD + COL_VM + d]);
#pragma unroll
    for (int j=0;j<8;++j){
      float f = Fs[s*8+j];
      float w = (1.f - f*beta[j])*gamma[j];
      Pa[j] *= w;
      Qa[j] = w*Qa[j] + f*vm;
    }
  }
#pragma unroll
  for (int j=0;j<8;++j){
    size_t idx = ((size_t)c*64 + mg*8 + j)*256 + d;
    CP[idx] = Pa[j]; CQ[idx] = Qa[j];
  }
}

__global__ __launch_bounds__(256) void k_scan2(const float* __restrict__ CP,
    const float* __restrict__ CQ, float* __restrict__ SIN){
  int m = blockIdx.x, d = threadIdx.x;
  float S = 0.f;
  for (int c = 0; c < 32; ++c){
    size_t idx = ((size_t)c*64 + m)*256 + d;
    SIN[idx] = S;
    S = CP[idx]*S + CQ[idx];
  }
}

__global__ __launch_bounds__(256) void k_scan3(const unsigned short* __restrict__ CC,
    const float* __restrict__ beta_p, const float* __restrict__ decay_p,
    const float* __restrict__ SIN, unsigned short* __restrict__ MEMS){
  int c = blockIdx.x, mg = blockIdx.y, d = threadIdx.x;
  __shared__ float Fs[512];
  for (int v = threadIdx.x; v < 512; v += 256){
    int s = v >> 3, j = v & 7;
    Fs[v] = sigmoidf_(b2f(CC[(size_t)(c*64+s)*CC_LD + COL_FG + mg*8 + j]));
  }
  __syncthreads();
  float beta[8], gamma[8], S[8];
#pragma unroll
  for (int j=0;j<8;++j){
    int m = mg*8+j;
    beta[j]  = sigmoidf_(beta_p[m*256+d]);
    gamma[j] = (d < 192) ? 1.f : sigmoidf_(decay_p[m*64 + (d-192)]);
    S[j] = SIN[((size_t)c*64 + m)*256 + d];
  }
  for (int s = 0; s < 64; ++s){
    float vm = b2f(CC[(size_t)(c*64+s)*CC_LD + COL_VM + d]);
    size_t tb = (size_t)(c*64+s)*64;
#pragma unroll
    for (int j=0;j<8;++j){
      float f = Fs[s*8+j];
      float w = (1.f - f*beta[j])*gamma[j];
      S[j] = w*S[j] + f*vm;
      MEMS[(tb + mg*8 + j)*256 + d] = f2b(S[j]);
    }
  }
}

// ---------------- mem readout (bf16 MEMS, bf16 strided QM) ----------------------
__global__ __launch_bounds__(256) void k_memread(const unsigned short* __restrict__ MEMS,
    const float* __restrict__ QH, const unsigned short* __restrict__ QMs, int qm_ld,
    const float* __restrict__ L, unsigned short* __restrict__ YMb){
  int t = blockIdx.x, tid = threadIdx.x;
  int wave = tid >> 6, lane = tid & 63;
  __shared__ float anorm[64];
  const unsigned short* Mt = MEMS + (size_t)t*16384;
  float4 qh4 = *(const float4*)(QH + (size_t)t*256 + lane*4);
  ushort4 qmu = *(const ushort4*)(QMs + (size_t)t*qm_ld + lane*4);
  float qm0 = b2f(qmu.x), qm1 = b2f(qmu.y), qm2 = b2f(qmu.z), qm3 = b2f(qmu.w);
  for (int mi = 0; mi < 16; ++mi){
    int m = wave*16 + mi;
    ushort4 su = *(const ushort4*)(Mt + m*256 + lane*4);
    float4 l4 = *(const float4*)(L + (size_t)m*256 + lane*4);
    float p = b2f(su.x)*qh4.x + b2f(su.y)*qh4.y + b2f(su.z)*qh4.z + b2f(su.w)*qh4.w
            + l4.x*qm0 + l4.y*qm1 + l4.z*qm2 + l4.w*qm3;
#pragma unroll
    for (int off = 32; off > 0; off >>= 1) p += __shfl_down(p, off);
    if (lane == 0) anorm[m] = p * (1.f/16.f);
  }
  __syncthreads();
  if (tid == 0){
    float mx = -INFINITY;
    for (int i = 0; i < 64; ++i) mx = fmaxf(mx, anorm[i]);
    float sum = 0.f;
    for (int i = 0; i < 64; ++i){ float e = expf(anorm[i]-mx); anorm[i] = e; sum += e; }
    float r = 1.f/sum;
    for (int i = 0; i < 64; ++i) anorm[i] *= r;
  }
  __syncthreads();
  float acc = 0.f;
  for (int m = 0; m < 64; ++m) acc += anorm[m]*b2f(Mt[m*256 + tid]);
  YMb[(size_t)t*256 + tid] = f2b(acc);
}

// ---------------- elementwise ----------------------------------------------------
__global__ void k_add3(const float* __restrict__ a, const float* __restrict__ b,
                       const float* __restrict__ c, float* __restrict__ o, int n4){
  int i = blockIdx.x*256 + threadIdx.x;
  if (i < n4){
    float4 x = ((const float4*)a)[i], y = ((const float4*)b)[i], z = ((const float4*)c)[i];
    float4 r; r.x=x.x+y.x+z.x; r.y=x.y+y.y+z.y; r.z=x.z+y.z+z.z; r.w=x.w+y.w+z.w;
    ((float4*)o)[i] = r;
  }
}

// silu(h1)*h2 from bf16 concat H12b [2048][5632] -> bf16 H1b [2048][2816]
__global__ void k_silumul_b2(const unsigned short* __restrict__ H12b,
                             unsigned short* __restrict__ H1b, int n4){
  int i = blockIdx.x*256 + threadIdx.x;
  if (i < n4){
    int r = i / 704, c4 = i % 704;
    ushort4 a4 = *(const ushort4*)(H12b + (size_t)r*5632 + c4*4);
    ushort4 b4 = *(const ushort4*)(H12b + (size_t)r*5632 + 2816 + c4*4);
    float ax = b2f(a4.x), ay = b2f(a4.y), az = b2f(a4.z), aw = b2f(a4.w);
    ushort4 o;
    o.x = f2b(ax*sigmoidf_(ax)*b2f(b4.x));
    o.y = f2b(ay*sigmoidf_(ay)*b2f(b4.y));
    o.z = f2b(az*sigmoidf_(az)*b2f(b4.z));
    o.w = f2b(aw*sigmoidf_(aw)*b2f(b4.w));
    ((ushort4*)H1b)[i] = o;
  }
}

// ---------------- launch ---------------------------------------------------------
extern "C" void kernel_launch(void* const* d_in, const int* in_sizes, int n_in,
                              void* d_out, int out_size, void* d_ws, size_t ws_size,
                              hipStream_t stream){
  const float* xs        = (const float*)d_in[0];
  const float* attn_q    = (const float*)d_in[1];
  const float* attn_k    = (const float*)d_in[2];
  const float* attn_v    = (const float*)d_in[3];
  const float* attn_o    = (const float*)d_in[4];
  const float* attn_r    = (const float*)d_in[5];
  const float* mem_f     = (const float*)d_in[6];
  const float* mem_q     = (const float*)d_in[7];
  const float* mem_k     = (const float*)d_in[8];
  const float* mem_v     = (const float*)d_in[9];
  const float* mem_o     = (const float*)d_in[10];
  const float* mem_r     = (const float*)d_in[11];
  const float* mem_beta  = (const float*)d_in[12];
  const float* mem_decay = (const float*)d_in[13];
  const float* mem_l     = (const float*)d_in[14];
  const float* ff1       = (const float*)d_in[15];
  const float* ff2       = (const float*)d_in[16];
  const float* ffo       = (const float*)d_in[17];
  const float* sn1       = (const float*)d_in[18];
  const float* sn2       = (const float*)d_in[19];
  float* out = (float*)d_out;
  float* W = (float*)d_ws;

  // ---- workspace layout (float offsets), ~226 MB ----
  unsigned short* XNb  = (unsigned short*)(W + 0);           // 2,097,152
  unsigned short* AVB  = (unsigned short*)(W + 2097152);     // 2,097,152
  unsigned short* WC2  = (unsigned short*)(W + 4194304);     // 5,111,808
  unsigned short* Vb   = (unsigned short*)(W + 9306112);     // 2,097,152
  unsigned short* CCb  = (unsigned short*)(W + 11403264);    // 5,111,808 (2048x4992 bf16)
  unsigned short* AOB  = (unsigned short*)(W + 16515072);    // 2,097,152
  unsigned short* MOB  = (unsigned short*)(W + 18612224);    // 262,144
  unsigned short* FFW  = (unsigned short*)(W + 18874368);    // 5,767,168
  unsigned short* FFOB = (unsigned short*)(W + 24641536);    // 2,883,584
  unsigned short* AKB  = (unsigned short*)(W + 27525120);    // 32,768
  unsigned short* MKTB = (unsigned short*)(W + 27557888);    // 32,768
  unsigned short* Ybb  = (unsigned short*)(W + 27590656);    // 2,097,152
  float*          B2f  = W + 29687808;                       // 4,194,304
  float*          XS2  = W + 33882112;                       // 4,194,304
  unsigned short* MEMSb= (unsigned short*)(W + 38076416);    // 16,777,216
  float*          CP   = W + 54853632;                       // 524,288
  float*          CQ   = W + 55377920;                       // 524,288
  float*          SIN  = W + 55902208;                       // 524,288
  // aliases (sequential liveness):
  float2*         TRIG = (float2*)(W + 0);                   // over XNb (dead after V/CC GEMMs)
  float*          K0   = W + 32768;                          // over XNb
  unsigned short* P    = (unsigned short*)(W + 557056);      // over XNb
  float*          QH   = W + 688128;                         // over XNb
  unsigned short* YMb  = (unsigned short*)(W + 1212416);     // over XNb
  float*          B1f  = W + 2097152;                        // over AVB+WC2 head (dead)
  unsigned short* XN2b = MEMSb;                              // over MEMSb (dead after memread)
  unsigned short* H1b  = (unsigned short*)(W + 40173568);    // over MEMSb tail
  unsigned short* H12b = CCb;                                // over CCb (+AOB head), dead by FF

  dim3 blk(256);

  // ---- weight conversions ----
  k_f2b<<<dim3(4096), blk, 0, stream>>>(attn_v, AVB, 1048576);
  k_f2b<<<dim3(4096), blk, 0, stream>>>(attn_r, WC2 + 0,       1048576);
  k_f2b<<<dim3(4096), blk, 0, stream>>>(mem_r,  WC2 + 4194304, 1048576);
  k_f2b<<<dim3(512),  blk, 0, stream>>>(attn_q, WC2 + 8388608, 131072);
  k_f2b<<<dim3(512),  blk, 0, stream>>>(mem_v,  WC2 + 8912896, 131072);
  k_f2b<<<dim3(512),  blk, 0, stream>>>(mem_q,  WC2 + 9437184, 131072);
  k_f2b<<<dim3(128),  blk, 0, stream>>>(mem_f,  WC2 + 9961472, 32768);
  hipMemsetAsync(WC2 + 10092544, 0, 262144, stream);   // pad rows 4928..4991
  k_f2b<<<dim3(4096), blk, 0, stream>>>(attn_o, AOB, 1048576);
  k_f2b<<<dim3(512),  blk, 0, stream>>>(mem_o,  MOB, 131072);
  k_f2b<<<dim3(5632), blk, 0, stream>>>(ff1, FFW + 0,       1441792);
  k_f2b<<<dim3(5632), blk, 0, stream>>>(ff2, FFW + 5767168, 1441792);
  k_f2b<<<dim3(5632), blk, 0, stream>>>(ffo, FFOB, 1441792);
  k_f2b<<<dim3(64),   blk, 0, stream>>>(attn_k, AKB, 16384);
  k_f2bT<<<dim3(256), blk, 0, stream>>>(mem_k, MKTB);

  // ---- xn = scale_norm(xs, g1) -> bf16 ----
  k_scalenorm_b<<<dim3(2048), blk, 0, stream>>>(xs, sn1, XNb);

  // ---- V (bf16 out) + concat CC (bf16 out) GEMMs ----
  k_gemm_bf2<<<dim3(32, 16), blk, 0, stream>>>(XNb, 2048, AVB, nullptr, Vb, 2048, 2048, 2048, 3, nullptr, nullptr, 0);
  k_gemm_bf2<<<dim3(78, 16), blk, 0, stream>>>(XNb, 2048, WC2, nullptr, CCb, CC_LD, 2048, CC_LD, 3, nullptr, nullptr, 0);

  // ---- trig table (XNb region now dead) ----
  k_trig<<<dim3(64), blk, 0, stream>>>(TRIG);

  // ---- attention ----
  k_gemm_bf2<<<dim3(4, 16), blk, 0, stream>>>(CCb + COL_QB, CC_LD, AKB, K0, nullptr, 256, 256, 256, 0, nullptr, nullptr, 0);
  k_attn_scores_mfma<<<dim3(32), blk, 0, stream>>>(CCb + COL_QB, K0, TRIG, P);
  k_attn_pv_mfma<<<dim3(16, 32), blk, 0, stream>>>(P, Vb, Ybb);
  k_gemm_bf2<<<dim3(32, 16), blk, 0, stream>>>(Ybb, 2048, AOB, B1f, nullptr, 2048, 2048, 2048, 2, nullptr, CCb + COL_B1, CC_LD);

  // ---- memory branch ----
  k_scan1<<<dim3(32, 8), blk, 0, stream>>>(CCb, mem_beta, mem_decay, CP, CQ);
  k_scan2<<<dim3(64), blk, 0, stream>>>(CP, CQ, SIN);
  k_scan3<<<dim3(32, 8), blk, 0, stream>>>(CCb, mem_beta, mem_decay, SIN, MEMSb);
  k_gemm_bf2<<<dim3(4, 16), blk, 0, stream>>>(CCb + COL_QM, CC_LD, MKTB, QH, nullptr, 256, 256, 256, 0, nullptr, nullptr, 0);
  k_memread<<<dim3(2048), blk, 0, stream>>>(MEMSb, QH, CCb + COL_QM, CC_LD, mem_l, YMb);
  k_gemm_bf2<<<dim3(32, 16), blk, 0, stream>>>(YMb, 256, MOB, B2f, nullptr, 2048, 256, 2048, 2, nullptr, CCb + COL_B2, CC_LD);

  // xs2 = attn_out + mem_out + xs
  k_add3<<<dim3(4096), blk, 0, stream>>>(B1f, B2f, xs, XS2, 1048576);

  // ---- FF ----
  k_scalenorm_b<<<dim3(2048), blk, 0, stream>>>(XS2, sn2, XN2b);
  k_gemm_bf2<<<dim3(88, 16), blk, 0, stream>>>(XN2b, 2048, FFW, nullptr, H12b, 5632, 2048, 5632, 3, nullptr, nullptr, 0);
  k_silumul_b2<<<dim3(5632), blk, 0, stream>>>(H12b, H1b, 1441792);
  k_gemm_bf2<<<dim3(32, 16), blk, 0, stream>>>(H1b, 2816, FFOB, out, nullptr, 2048, 2816, 2048, 0, XS2, nullptr, 0);
}

// Round 5
// 474.989 us; speedup vs baseline: 6.4328x; 1.2411x over previous
//
#include <hip/hip_runtime.h>
#include <math.h>

// RAMEN layer. Round 5: pipelined GEMM (3-buf LDS rotation, counted vmcnt,
// swizzled ds_read), V merged into concat GEMM, fused weight conversion.
// T=2048, X_D=2048, M_D=256, M_N=64, CHUNK=64, FF_D=2816.

typedef short bhalf8 __attribute__((ext_vector_type(8)));
typedef float f32x4 __attribute__((ext_vector_type(4)));

#define CC_LD 7168
#define COL_V   0
#define COL_B1  2048
#define COL_B2  4096
#define COL_QB  6144
#define COL_VM  6400
#define COL_QM  6656
#define COL_FG  6912

#define AS1 __attribute__((address_space(1)))
#define AS3 __attribute__((address_space(3)))

__device__ __forceinline__ float sigmoidf_(float x){ return 1.0f/(1.0f+expf(-x)); }

__device__ __forceinline__ unsigned short f2b(float f){
  unsigned u = __float_as_uint(f);
  unsigned r = (u + 0x7fffu + ((u>>16)&1u)) >> 16;
  return (unsigned short)r;
}
__device__ __forceinline__ float b2f(unsigned short h){
  return __uint_as_float(((unsigned)h)<<16);
}

// ---------------- fused f32 -> bf16 conversion of ALL weights -------------------
__global__ void k_f2b_all(
    const float* __restrict__ av, const float* __restrict__ ar, const float* __restrict__ mr,
    const float* __restrict__ aq, const float* __restrict__ mv, const float* __restrict__ mq,
    const float* __restrict__ mf, const float* __restrict__ ao, const float* __restrict__ mo,
    const float* __restrict__ f1, const float* __restrict__ f2, const float* __restrict__ fo,
    const float* __restrict__ ak,
    unsigned short* __restrict__ WCAT, unsigned short* __restrict__ AOB,
    unsigned short* __restrict__ MOB, unsigned short* __restrict__ FFW,
    unsigned short* __restrict__ FFOB, unsigned short* __restrict__ AKB){
  int i = blockIdx.x*256 + threadIdx.x;  // float4 index
  const float* s; unsigned short* d; int off;
  if (i < 3571712){
    d = WCAT + (size_t)i*4;
    if      (i < 1048576){ s = av; off = i; }
    else if (i < 2097152){ s = ar; off = i-1048576; }
    else if (i < 3145728){ s = mr; off = i-2097152; }
    else if (i < 3276800){ s = aq; off = i-3145728; }
    else if (i < 3407872){ s = mv; off = i-3276800; }
    else if (i < 3538944){ s = mq; off = i-3407872; }
    else                 { s = mf; off = i-3538944; }
  }
  else if (i < 4620288){ off = i-3571712; s = ao; d = AOB  + (size_t)off*4; }
  else if (i < 4751360){ off = i-4620288; s = mo; d = MOB  + (size_t)off*4; }
  else if (i < 6193152){ off = i-4751360; s = f1; d = FFW  + (size_t)off*4; }
  else if (i < 7634944){ off = i-6193152; s = f2; d = FFW  + (size_t)(off+1441792)*4; }
  else if (i < 9076736){ off = i-7634944; s = fo; d = FFOB + (size_t)off*4; }
  else if (i < 9093120){ off = i-9076736; s = ak; d = AKB  + (size_t)off*4; }
  else return;
  float4 v = ((const float4*)s)[off];
  ushort4 o;
  o.x = f2b(v.x); o.y = f2b(v.y); o.z = f2b(v.z); o.w = f2b(v.w);
  *(ushort4*)d = o;
}

// transpose + convert for 256x256 (mem_k): d[n][k] = s[k][n]
__global__ void k_f2bT(const float* __restrict__ s, unsigned short* __restrict__ d){
  int i = blockIdx.x, j = threadIdx.x;
  d[(size_t)j*256 + i] = f2b(s[(size_t)i*256 + j]);
}

// ---------------- trig table: TR[pos][j] = (cos, sin)(pos * 10000^-(j/128)) -----
__global__ void k_trig(float2* __restrict__ TR){
  int idx = blockIdx.x*256 + threadIdx.x;   // 16384
  int pos = idx >> 7, j = idx & 127;
  float inv = powf(10000.f, -(float)j/128.f);
  float a = (float)pos * inv;
  TR[idx] = make_float2(cosf(a), sinf(a));
}

// ---------------- scale norm -> bf16 --------------------------------------------
__global__ __launch_bounds__(256) void k_scalenorm_b(const float* __restrict__ x,
    const float* __restrict__ g, unsigned short* __restrict__ ob){
  int row = blockIdx.x, tid = threadIdx.x;
  const float* xr = x + (size_t)row*2048;
  float ss = 0.f;
  for (int j = tid; j < 2048; j += 256){ float v = xr[j]; ss += v*v; }
  __shared__ float red[256];
  red[tid] = ss; __syncthreads();
  for (int s = 128; s > 0; s >>= 1){ if (tid < s) red[tid] += red[tid+s]; __syncthreads(); }
  float scale = g[0] / (sqrtf(red[0]) + 1e-8f);
  unsigned short* orow = ob + (size_t)row*2048;
  for (int j4 = tid; j4 < 512; j4 += 256){
    float4 v = *(const float4*)(xr + j4*4);
    ushort4 o;
    o.x = f2b(v.x*scale); o.y = f2b(v.y*scale); o.z = f2b(v.z*scale); o.w = f2b(v.w*scale);
    ((ushort4*)orow)[j4] = o;
  }
}

// ---------------- pipelined bf16 MFMA GEMM: C[M,N] = A[M,K](lda) @ B[N,K]^T -----
// 128x128 tile, BK=32, 4 waves, 3 LDS buffers (depth-2 prefetch, counted vmcnt).
// LDS read swizzle: granule ^= row&3 (inverse-permuted global source).
// epi: 0 -> C f32 (+add); 2 -> C f32 = v*sigmoid(b2f(gate)); 3 -> Cb bf16.
__global__ __launch_bounds__(256) void k_gemm_p(
    const unsigned short* __restrict__ A, int lda,
    const unsigned short* __restrict__ B,
    float* __restrict__ C, unsigned short* __restrict__ Cb,
    int N, int K, int ldc, int epi,
    const float* __restrict__ add,
    const unsigned short* __restrict__ gate, int gate_ld){
  __shared__ unsigned short LDSu[24576];     // 3 x (A 4096 + B 4096) elems = 48 KB
  int tid = threadIdx.x;
  int w = tid >> 6, l = tid & 63;
  int bi = blockIdx.y, bj = blockIdx.x;
  int m0 = bi*128, n0 = bj*128;
  int wr = w >> 1, wc = w & 1;

  f32x4 acc[4][4];
#pragma unroll
  for (int i=0;i<4;++i)
#pragma unroll
    for (int j=0;j<4;++j){ f32x4 z = {0.f,0.f,0.f,0.f}; acc[i][j] = z; }

  // staging geometry: per op, thread tid covers LDS row (tid>>2), dest granule (tid&3)
  const int r0 = tid >> 2;
  const int gsrc8 = (((tid&3) ^ (r0&3)) * 8);   // inverse-swizzled source granule

  auto stage = [&](int bs, int kt){
    unsigned short* db = LDSu + bs*8192;
    const unsigned short* ap0 = A + (size_t)(m0 + r0)*lda      + kt*32 + gsrc8;
    const unsigned short* ap1 = A + (size_t)(m0 + 64 + r0)*lda + kt*32 + gsrc8;
    const unsigned short* bp0 = B + (size_t)(n0 + r0)*K        + kt*32 + gsrc8;
    const unsigned short* bp1 = B + (size_t)(n0 + 64 + r0)*K   + kt*32 + gsrc8;
    __builtin_amdgcn_global_load_lds((const AS1 void*)ap0, (AS3 void*)(db + tid*8),        16, 0, 0);
    __builtin_amdgcn_global_load_lds((const AS1 void*)ap1, (AS3 void*)(db + 2048 + tid*8), 16, 0, 0);
    __builtin_amdgcn_global_load_lds((const AS1 void*)bp0, (AS3 void*)(db + 4096 + tid*8), 16, 0, 0);
    __builtin_amdgcn_global_load_lds((const AS1 void*)bp1, (AS3 void*)(db + 6144 + tid*8), 16, 0, 0);
  };

  const int nt = K >> 5;
  // prologue: stage T0,T1; wait T0 (8 outstanding -> 4); barrier
  stage(0, 0);
  stage(1, 1);
  asm volatile("s_waitcnt vmcnt(4)" ::: "memory");
  __builtin_amdgcn_s_barrier();

  const int lr = l & 15;
  const int gsw = (((l>>4) ^ (l&3)) * 8);       // swizzled read granule
  const int aoff = (wr*64 + lr)*32 + gsw;
  const int boff = 4096 + (wc*64 + lr)*32 + gsw;

  int cur = 0;
  for (int t = 0; t < nt; ++t){
    if (t + 2 < nt) stage((t+2)%3, t+2);
    const unsigned short* Tb = LDSu + cur*8192;
    bhalf8 af[4], bfr[4];
#pragma unroll
    for (int m=0;m<4;++m) af[m]  = *(const bhalf8*)(Tb + aoff + m*512);
#pragma unroll
    for (int n=0;n<4;++n) bfr[n] = *(const bhalf8*)(Tb + boff + n*512);
    __builtin_amdgcn_s_setprio(1);
#pragma unroll
    for (int m=0;m<4;++m)
#pragma unroll
      for (int n=0;n<4;++n)
        acc[m][n] = __builtin_amdgcn_mfma_f32_16x16x32_bf16(af[m], bfr[n], acc[m][n], 0, 0, 0);
    __builtin_amdgcn_s_setprio(0);
    if (t + 1 < nt){
      if (t + 2 < nt){ asm volatile("s_waitcnt vmcnt(4)" ::: "memory"); }
      else           { asm volatile("s_waitcnt vmcnt(0)" ::: "memory"); }
      __builtin_amdgcn_s_barrier();
      cur = (cur == 2) ? 0 : cur + 1;
    }
  }

#pragma unroll
  for (int m=0;m<4;++m){
    int rowb = m0 + wr*64 + m*16 + ((l>>4)<<2);
#pragma unroll
    for (int r=0;r<4;++r){
      int row = rowb + r;
      size_t rbase = (size_t)row*ldc;
      size_t gbase = (size_t)row*gate_ld;
#pragma unroll
      for (int n=0;n<4;++n){
        int col = n0 + wc*64 + n*16 + (l&15);
        float v = acc[m][n][r];
        if (add) v += add[rbase + col];
        if (epi == 2) v *= sigmoidf_(b2f(gate[gbase + col]));
        if (epi == 3) Cb[rbase + col] = f2b(v);
        else          C[rbase + col] = v;
      }
    }
  }
}

// ---------------- fused attention scores+softmax (MFMA) -------------------------
__global__ __launch_bounds__(256) void k_attn_scores_mfma(
    const unsigned short* __restrict__ CCqb, const float* __restrict__ K0,
    const float2* __restrict__ TR, unsigned short* __restrict__ P){
  __shared__ unsigned short Ks[128*256];   // 64 KB
  int c = blockIdx.x, tid = threadIdx.x;
  for (int it = 0; it < 16; ++it){
    int id = tid + it*256;          // 0..4095
    int m = id >> 5;                // key row 0..127, rope pos = m
    int cs = (id & 31) * 8;         // f32 col start
    float v[8];
    if (c == 0 && m < 64){
#pragma unroll
      for (int u=0;u<8;++u) v[u] = 0.f;
    } else {
      int gr = (c-1)*64 + m;
      const float* kr = K0 + (size_t)gr*256 + cs;
      float4 x0 = *(const float4*)kr, x1 = *(const float4*)(kr+4);
      v[0]=x0.x; v[1]=x0.y; v[2]=x0.z; v[3]=x0.w;
      v[4]=x1.x; v[5]=x1.y; v[6]=x1.z; v[7]=x1.w;
#pragma unroll
      for (int p2=0;p2<4;++p2){
        float2 t = TR[m*128 + (cs>>1) + p2];
        float e = v[2*p2], o = v[2*p2+1];
        v[2*p2]   = e*t.x - o*t.y;
        v[2*p2+1] = o*t.x + e*t.y;
      }
    }
    unsigned short pk[8];
#pragma unroll
    for (int u=0;u<8;++u) pk[u] = f2b(v[u]);
    int byte = m*512 + ((cs*2) ^ ((m&7)<<4));
    *(bhalf8*)((char*)&Ks[0] + byte) = *(const bhalf8*)pk;
  }
  __syncthreads();

  int w = tid >> 6, l = tid & 63;
  int lr = l & 15, lkg = l >> 4;
  f32x4 acc[8];
#pragma unroll
  for (int n=0;n<8;++n){ f32x4 z = {0.f,0.f,0.f,0.f}; acc[n] = z; }

  int iq = w*16 + lr;
  const unsigned short* qbase = CCqb + (size_t)(c*64 + iq)*CC_LD;
  int pos = 64 + iq;

  for (int kt = 0; kt < 8; ++kt){
    int k0c = kt*32 + lkg*8;
    bhalf8 q8 = *(const bhalf8*)(qbase + k0c);
    float v[8];
#pragma unroll
    for (int u=0;u<8;++u) v[u] = b2f((unsigned short)(((short*)&q8)[u]));
#pragma unroll
    for (int p2=0;p2<4;++p2){
      float2 t = TR[pos*128 + (k0c>>1) + p2];
      float e = v[2*p2], o = v[2*p2+1];
      v[2*p2]   = e*t.x - o*t.y;
      v[2*p2+1] = o*t.x + e*t.y;
    }
    unsigned short pk[8];
#pragma unroll
    for (int u=0;u<8;++u) pk[u] = f2b(v[u]);
    bhalf8 af = *(const bhalf8*)pk;
#pragma unroll
    for (int n=0;n<8;++n){
      int m = n*16 + lr;
      int byte = m*512 + ((k0c*2) ^ ((m&7)<<4));
      bhalf8 bf = *(const bhalf8*)((const char*)&Ks[0] + byte);
      acc[n] = __builtin_amdgcn_mfma_f32_16x16x32_bf16(af, bf, acc[n], 0, 0, 0);
    }
  }

  int i0 = w*16 + lkg*4;
  float mx[4] = {-1e30f,-1e30f,-1e30f,-1e30f};
  float sm[4] = {0.f,0.f,0.f,0.f};
#pragma unroll
  for (int n=0;n<8;++n){
    int col = n*16 + lr;
#pragma unroll
    for (int r=0;r<4;++r){
      float vv = acc[n][r] * (1.f/16.f);
      if (col > i0 + r + 64) vv = -1e30f;
      acc[n][r] = vv;
      mx[r] = fmaxf(mx[r], vv);
    }
  }
#pragma unroll
  for (int s=1; s<16; s<<=1)
#pragma unroll
    for (int r=0;r<4;++r) mx[r] = fmaxf(mx[r], __shfl_xor(mx[r], s));
#pragma unroll
  for (int n=0;n<8;++n)
#pragma unroll
    for (int r=0;r<4;++r){
      float e = expf(acc[n][r] - mx[r]);
      acc[n][r] = e; sm[r] += e;
    }
#pragma unroll
  for (int s=1; s<16; s<<=1)
#pragma unroll
    for (int r=0;r<4;++r) sm[r] += __shfl_xor(sm[r], s);
  float rcp[4];
#pragma unroll
  for (int r=0;r<4;++r) rcp[r] = 1.f/sm[r];

  unsigned short* Pr = P + (size_t)c*8192;
#pragma unroll
  for (int n=0;n<8;++n){
    int col = n*16 + lr;
#pragma unroll
    for (int r=0;r<4;++r)
      Pr[(i0+r)*128 + col] = f2b(acc[n][r]*rcp[r]);
  }
}

// ---------------- MFMA PV: Y[c*64+i, ct*128+:] = P[c] @ V2[c] -------------------
__global__ __launch_bounds__(256) void k_attn_pv_mfma(
    const unsigned short* __restrict__ P, const unsigned short* __restrict__ Vb, int vld,
    unsigned short* __restrict__ Y){
  __shared__ unsigned short Vt[128*128];   // [col][k] swizzled, 32 KB
  int ct = blockIdx.x, c = blockIdx.y, tid = threadIdx.x;
  {
    int k = tid >> 1;               // V2 row 0..127
    int ch = (tid & 1) * 64;        // col half
    if (c == 0 && k < 64){
      for (int u=0; u<64; ++u){
        int col = ch + u;
        int byte = col*256 + ((k*2) ^ ((col&7)<<4));
        *(unsigned short*)((char*)&Vt[0] + byte) = 0;
      }
    } else {
      int gr = (c-1)*64 + k;
      const unsigned short* vr = Vb + (size_t)gr*vld + ct*128 + ch;
      for (int u8=0; u8<8; ++u8){
        bhalf8 x = *(const bhalf8*)(vr + u8*8);
#pragma unroll
        for (int u=0;u<8;++u){
          int col = ch + u8*8 + u;
          int byte = col*256 + ((k*2) ^ ((col&7)<<4));
          *(unsigned short*)((char*)&Vt[0] + byte) = (unsigned short)(((short*)&x)[u]);
        }
      }
    }
  }
  __syncthreads();
  int w = tid >> 6, l = tid & 63, lr = l & 15, lkg = l >> 4;
  f32x4 acc[8];
#pragma unroll
  for (int n=0;n<8;++n){ f32x4 z = {0.f,0.f,0.f,0.f}; acc[n] = z; }
  const unsigned short* Pr = P + (size_t)c*8192;
  for (int kt=0; kt<4; ++kt){
    int kb = kt*32 + lkg*8;
    bhalf8 af = *(const bhalf8*)(Pr + (w*16 + lr)*128 + kb);
#pragma unroll
    for (int n=0;n<8;++n){
      int col = n*16 + lr;
      int byte = col*256 + ((kb*2) ^ ((col&7)<<4));
      bhalf8 bf = *(const bhalf8*)((const char*)&Vt[0] + byte);
      acc[n] = __builtin_amdgcn_mfma_f32_16x16x32_bf16(af, bf, acc[n], 0, 0, 0);
    }
  }
  int row0 = c*64 + w*16 + lkg*4;
#pragma unroll
  for (int n=0;n<8;++n){
    int col = ct*128 + n*16 + lr;
#pragma unroll
    for (int r=0;r<4;++r)
      Y[(size_t)(row0+r)*2048 + col] = f2b(acc[n][r]);
  }
}

// ---------------- mem scan, 8 memories per block (CC bf16) ----------------------
__global__ __launch_bounds__(256) void k_scan1(const unsigned short* __restrict__ CC,
    const float* __restrict__ beta_p, const float* __restrict__ decay_p,
    float* __restrict__ CP, float* __restrict__ CQ){
  int c = blockIdx.x, mg = blockIdx.y, d = threadIdx.x;
  __shared__ float Fs[512];
  for (int v = threadIdx.x; v < 512; v += 256){
    int s = v >> 3, j = v & 7;
    Fs[v] = sigmoidf_(b2f(CC[(size_t)(c*64+s)*CC_LD + COL_FG + mg*8 + j]));
  }
  __syncthreads();
  float beta[8], gamma[8], Pa[8], Qa[8];
#pragma unroll
  for (int j=0;j<8;++j){
    int m = mg*8+j;
    beta[j]  = sigmoidf_(beta_p[m*256+d]);
    gamma[j] = (d < 192) ? 1.f : sigmoidf_(decay_p[m*64 + (d-192)]);
    Pa[j] = 1.f; Qa[j] = 0.f;
  }
  for (int s = 0; s < 64; ++s){
    float vm = b2f(CC[(size_t)(c*64+s)*CC_LD + COL_VM + d]);
#pragma unroll
    for (int j=0;j<8;++j){
      float f = Fs[s*8+j];
      float w = (1.f - f*beta[j])*gamma[j];
      Pa[j] *= w;
      Qa[j] = w*Qa[j] + f*vm;
    }
  }
#pragma unroll
  for (int j=0;j<8;++j){
    size_t idx = ((size_t)c*64 + mg*8 + j)*256 + d;
    CP[idx] = Pa[j]; CQ[idx] = Qa[j];
  }
}

__global__ __launch_bounds__(256) void k_scan2(const float* __restrict__ CP,
    const float* __restrict__ CQ, float* __restrict__ SIN){
  int m = blockIdx.x, d = threadIdx.x;
  float S = 0.f;
  for (int c = 0; c < 32; ++c){
    size_t idx = ((size_t)c*64 + m)*256 + d;
    SIN[idx] = S;
    S = CP[idx]*S + CQ[idx];
  }
}

__global__ __launch_bounds__(256) void k_scan3(const unsigned short* __restrict__ CC,
    const float* __restrict__ beta_p, const float* __restrict__ decay_p,
    const float* __restrict__ SIN, unsigned short* __restrict__ MEMS){
  int c = blockIdx.x, mg = blockIdx.y, d = threadIdx.x;
  __shared__ float Fs[512];
  for (int v = threadIdx.x; v < 512; v += 256){
    int s = v >> 3, j = v & 7;
    Fs[v] = sigmoidf_(b2f(CC[(size_t)(c*64+s)*CC_LD + COL_FG + mg*8 + j]));
  }
  __syncthreads();
  float beta[8], gamma[8], S[8];
#pragma unroll
  for (int j=0;j<8;++j){
    int m = mg*8+j;
    beta[j]  = sigmoidf_(beta_p[m*256+d]);
    gamma[j] = (d < 192) ? 1.f : sigmoidf_(decay_p[m*64 + (d-192)]);
    S[j] = SIN[((size_t)c*64 + m)*256 + d];
  }
  for (int s = 0; s < 64; ++s){
    float vm = b2f(CC[(size_t)(c*64+s)*CC_LD + COL_VM + d]);
    size_t tb = (size_t)(c*64+s)*64;
#pragma unroll
    for (int j=0;j<8;++j){
      float f = Fs[s*8+j];
      float w = (1.f - f*beta[j])*gamma[j];
      S[j] = w*S[j] + f*vm;
      MEMS[(tb + mg*8 + j)*256 + d] = f2b(S[j]);
    }
  }
}

// ---------------- mem readout (bf16 MEMS, bf16 strided QM) ----------------------
__global__ __launch_bounds__(256) void k_memread(const unsigned short* __restrict__ MEMS,
    const float* __restrict__ QH, const unsigned short* __restrict__ QMs, int qm_ld,
    const float* __restrict__ L, unsigned short* __restrict__ YMb){
  int t = blockIdx.x, tid = threadIdx.x;
  int wave = tid >> 6, lane = tid & 63;
  __shared__ float anorm[64];
  const unsigned short* Mt = MEMS + (size_t)t*16384;
  float4 qh4 = *(const float4*)(QH + (size_t)t*256 + lane*4);
  ushort4 qmu = *(const ushort4*)(QMs + (size_t)t*qm_ld + lane*4);
  float qm0 = b2f(qmu.x), qm1 = b2f(qmu.y), qm2 = b2f(qmu.z), qm3 = b2f(qmu.w);
  for (int mi = 0; mi < 16; ++mi){
    int m = wave*16 + mi;
    ushort4 su = *(const ushort4*)(Mt + m*256 + lane*4);
    float4 l4 = *(const float4*)(L + (size_t)m*256 + lane*4);
    float p = b2f(su.x)*qh4.x + b2f(su.y)*qh4.y + b2f(su.z)*qh4.z + b2f(su.w)*qh4.w
            + l4.x*qm0 + l4.y*qm1 + l4.z*qm2 + l4.w*qm3;
#pragma unroll
    for (int off = 32; off > 0; off >>= 1) p += __shfl_down(p, off);
    if (lane == 0) anorm[m] = p * (1.f/16.f);
  }
  __syncthreads();
  if (tid == 0){
    float mx = -INFINITY;
    for (int i = 0; i < 64; ++i) mx = fmaxf(mx, anorm[i]);
    float sum = 0.f;
    for (int i = 0; i < 64; ++i){ float e = expf(anorm[i]-mx); anorm[i] = e; sum += e; }
    float r = 1.f/sum;
    for (int i = 0; i < 64; ++i) anorm[i] *= r;
  }
  __syncthreads();
  float acc = 0.f;
  for (int m = 0; m < 64; ++m) acc += anorm[m]*b2f(Mt[m*256 + tid]);
  YMb[(size_t)t*256 + tid] = f2b(acc);
}

// ---------------- elementwise ----------------------------------------------------
__global__ void k_add3(const float* __restrict__ a, const float* __restrict__ b,
                       const float* __restrict__ c, float* __restrict__ o, int n4){
  int i = blockIdx.x*256 + threadIdx.x;
  if (i < n4){
    float4 x = ((const float4*)a)[i], y = ((const float4*)b)[i], z = ((const float4*)c)[i];
    float4 r; r.x=x.x+y.x+z.x; r.y=x.y+y.y+z.y; r.z=x.z+y.z+z.z; r.w=x.w+y.w+z.w;
    ((float4*)o)[i] = r;
  }
}

__global__ void k_silumul_b2(const unsigned short* __restrict__ H12b,
                             unsigned short* __restrict__ H1b, int n4){
  int i = blockIdx.x*256 + threadIdx.x;
  if (i < n4){
    int r = i / 704, c4 = i % 704;
    ushort4 a4 = *(const ushort4*)(H12b + (size_t)r*5632 + c4*4);
    ushort4 b4 = *(const ushort4*)(H12b + (size_t)r*5632 + 2816 + c4*4);
    float ax = b2f(a4.x), ay = b2f(a4.y), az = b2f(a4.z), aw = b2f(a4.w);
    ushort4 o;
    o.x = f2b(ax*sigmoidf_(ax)*b2f(b4.x));
    o.y = f2b(ay*sigmoidf_(ay)*b2f(b4.y));
    o.z = f2b(az*sigmoidf_(az)*b2f(b4.z));
    o.w = f2b(aw*sigmoidf_(aw)*b2f(b4.w));
    ((ushort4*)H1b)[i] = o;
  }
}

// ---------------- launch ---------------------------------------------------------
extern "C" void kernel_launch(void* const* d_in, const int* in_sizes, int n_in,
                              void* d_out, int out_size, void* d_ws, size_t ws_size,
                              hipStream_t stream){
  const float* xs        = (const float*)d_in[0];
  const float* attn_q    = (const float*)d_in[1];
  const float* attn_k    = (const float*)d_in[2];
  const float* attn_v    = (const float*)d_in[3];
  const float* attn_o    = (const float*)d_in[4];
  const float* attn_r    = (const float*)d_in[5];
  const float* mem_f     = (const float*)d_in[6];
  const float* mem_q     = (const float*)d_in[7];
  const float* mem_k     = (const float*)d_in[8];
  const float* mem_v     = (const float*)d_in[9];
  const float* mem_o     = (const float*)d_in[10];
  const float* mem_r     = (const float*)d_in[11];
  const float* mem_beta  = (const float*)d_in[12];
  const float* mem_decay = (const float*)d_in[13];
  const float* mem_l     = (const float*)d_in[14];
  const float* ff1       = (const float*)d_in[15];
  const float* ff2       = (const float*)d_in[16];
  const float* ffo       = (const float*)d_in[17];
  const float* sn1       = (const float*)d_in[18];
  const float* sn2       = (const float*)d_in[19];
  float* out = (float*)d_out;
  float* W = (float*)d_ws;

  // ---- workspace layout (float offsets), ~227 MB ----
  unsigned short* XNb  = (unsigned short*)(W + 0);           // 2,097,152
  unsigned short* WCAT = (unsigned short*)(W + 2097152);     // 7,340,032 (7168x2048)
  unsigned short* CCb  = (unsigned short*)(W + 9437184);     // 7,340,032 (2048x7168)
  unsigned short* AOB  = (unsigned short*)(W + 16777216);    // 2,097,152
  unsigned short* MOB  = (unsigned short*)(W + 18874368);    // 262,144
  unsigned short* FFW  = (unsigned short*)(W + 19136512);    // 5,767,168
  unsigned short* FFOB = (unsigned short*)(W + 24903680);    // 2,883,584
  unsigned short* AKB  = (unsigned short*)(W + 27787264);    // 32,768
  unsigned short* MKTB = (unsigned short*)(W + 27820032);    // 32,768
  unsigned short* Ybb  = (unsigned short*)(W + 27852800);    // 2,097,152
  float*          B2f  = W + 29949952;                       // 4,194,304
  float*          XS2  = W + 34144256;                       // 4,194,304
  unsigned short* MEMSb= (unsigned short*)(W + 38338560);    // 16,777,216
  float*          CP   = W + 55115776;                       // 524,288
  float*          CQ   = W + 55640064;                       // 524,288
  float*          SIN  = W + 56164352;                       // 524,288
  // aliases (sequential liveness):
  float2*         TRIG = (float2*)(W + 0);                   // over XNb (dead after CC GEMM)
  float*          K0   = W + 32768;                          // over XNb
  unsigned short* P    = (unsigned short*)(W + 557056);      // over XNb
  float*          QH   = W + 688128;                         // over XNb
  unsigned short* YMb  = (unsigned short*)(W + 1212416);     // over XNb
  float*          B1f  = W + 2097152;                        // over WCAT (dead after CC GEMM)
  unsigned short* XN2b = MEMSb;                              // over MEMSb (dead after memread)
  unsigned short* H1b  = (unsigned short*)(W + 40435712);    // over MEMSb tail
  unsigned short* H12b = CCb;                                // over CCb (dead by FF)

  dim3 blk(256);

  // ---- fused weight conversions ----
  k_f2b_all<<<dim3(35520), blk, 0, stream>>>(attn_v, attn_r, mem_r, attn_q, mem_v, mem_q,
      mem_f, attn_o, mem_o, ff1, ff2, ffo, attn_k, WCAT, AOB, MOB, FFW, FFOB, AKB);
  hipMemsetAsync(WCAT + 14286848, 0, 786432, stream);   // pad rows 6976..7167
  k_f2bT<<<dim3(256), blk, 0, stream>>>(mem_k, MKTB);

  // ---- xn = scale_norm(xs, g1) -> bf16 ----
  k_scalenorm_b<<<dim3(2048), blk, 0, stream>>>(xs, sn1, XNb);

  // ---- BIG concat GEMM (V + gates + QB + VM + QM + FG), bf16 out ----
  k_gemm_p<<<dim3(56, 16), blk, 0, stream>>>(XNb, 2048, WCAT, nullptr, CCb, CC_LD, 2048, CC_LD, 3, nullptr, nullptr, 0);

  // ---- trig table (XNb region now dead) ----
  k_trig<<<dim3(64), blk, 0, stream>>>(TRIG);

  // ---- attention ----
  k_gemm_p<<<dim3(2, 16), blk, 0, stream>>>(CCb + COL_QB, CC_LD, AKB, K0, nullptr, 256, 256, 256, 0, nullptr, nullptr, 0);
  k_attn_scores_mfma<<<dim3(32), blk, 0, stream>>>(CCb + COL_QB, K0, TRIG, P);
  k_attn_pv_mfma<<<dim3(16, 32), blk, 0, stream>>>(P, CCb + COL_V, CC_LD, Ybb);
  k_gemm_p<<<dim3(16, 16), blk, 0, stream>>>(Ybb, 2048, AOB, B1f, nullptr, 2048, 2048, 2048, 2, nullptr, CCb + COL_B1, CC_LD);

  // ---- memory branch ----
  k_scan1<<<dim3(32, 8), blk, 0, stream>>>(CCb, mem_beta, mem_decay, CP, CQ);
  k_scan2<<<dim3(64), blk, 0, stream>>>(CP, CQ, SIN);
  k_scan3<<<dim3(32, 8), blk, 0, stream>>>(CCb, mem_beta, mem_decay, SIN, MEMSb);
  k_gemm_p<<<dim3(2, 16), blk, 0, stream>>>(CCb + COL_QM, CC_LD, MKTB, QH, nullptr, 256, 256, 256, 0, nullptr, nullptr, 0);
  k_memread<<<dim3(2048), blk, 0, stream>>>(MEMSb, QH, CCb + COL_QM, CC_LD, mem_l, YMb);
  k_gemm_p<<<dim3(16, 16), blk, 0, stream>>>(YMb, 256, MOB, B2f, nullptr, 2048, 256, 2048, 2, nullptr, CCb + COL_B2, CC_LD);

  // xs2 = attn_out + mem_out + xs
  k_add3<<<dim3(4096), blk, 0, stream>>>(B1f, B2f, xs, XS2, 1048576);

  // ---- FF ----
  k_scalenorm_b<<<dim3(2048), blk, 0, stream>>>(XS2, sn2, XN2b);
  k_gemm_p<<<dim3(44, 16), blk, 0, stream>>>(XN2b, 2048, FFW, nullptr, H12b, 5632, 2048, 5632, 3, nullptr, nullptr, 0);
  k_silumul_b2<<<dim3(5632), blk, 0, stream>>>(H12b, H1b, 1441792);
  k_gemm_p<<<dim3(16, 16), blk, 0, stream>>>(H1b, 2816, FFOB, out, nullptr, 2048, 2816, 2048, 0, XS2, nullptr, 0);
}